// Round 1
// baseline (151369.751 us; speedup 1.0000x reference)
//
#include <hip/hip_runtime.h>
#include <hip/hip_bf16.h>
#include <math.h>

// ---------------- problem constants ----------------
#define BB 8
#define CC 64
#define TE 8
#define TT 512
#define RR 128
#define SS 128
#define QQ 256
#define LL 20
#define NTHR 512

// dilations are powers of two -> use masks
__constant__ int c_dil[LL] = {1,2,4,8,16,32,64,128,256,512,
                              1,2,4,8,16,32,64,128,256,512};
// per-layer float offset into one batch's dilation-buffer region (d*128 cumsum)
__constant__ int c_layoff[LL] = {0,128,384,896,1920,3968,8064,16256,32640,65408,
                                 130944,131072,131328,131840,132864,134912,139008,147200,163584,196352};

// ---------------- workspace layout (in floats) ----------------
// dilation buffers: 8 batches x 2046*128 floats
constexpr size_t BUF_PER_BATCH = 261888;           // 2046*128
constexpr size_t OFF_BUF    = 0;
constexpr size_t OFF_CAUSAL = 2095104;             // 8*261888
constexpr size_t OFF_RES    = OFF_CAUSAL + 1310720; // 20*2*32*256*4
constexpr size_t OFF_SKIP   = OFF_RES    + 327680;  // 20*32*128*4
constexpr size_t OFF_COND   = OFF_SKIP   + 327680;
constexpr size_t OFF_SKIPC  = OFF_COND   + 327680;  // 20*16*256*4
constexpr size_t OFF_FC     = OFF_SKIPC  + 16384;
constexpr size_t OFF_CONDF  = OFF_FC     + 16384;
constexpr size_t OFF_LOGITS = OFF_CONDF  + 8192;
// end = OFF_LOGITS + 32768 = 4,462,592 floats = ~17.9 MB

// ============================================================
// prep: transpose all weight matrices into [kgroup][out][4] float4 layout
// total float4 elements: 591872
// ============================================================
__global__ void wn_prep(const float* __restrict__ cw,   // causal_w (20,256,128,2)
                        const float* __restrict__ dw,   // cond_w   (20,256,64)
                        const float* __restrict__ rw,   // res_w    (20,128,128)
                        const float* __restrict__ sw,   // skip_w   (20,128,128)
                        const float* __restrict__ scw,  // skipc_w  (128,128)
                        const float* __restrict__ fw,   // fc_w     (128,128)
                        const float* __restrict__ cfw,  // condf_w  (128,64)
                        const float* __restrict__ lw,   // logits_w (256,128)
                        float* __restrict__ ws)
{
    int g = blockIdx.x * blockDim.x + threadIdx.x;
    if (g >= 591872) return;
    float4 v;
    float* dst;
    if (g < 327680) {                       // causalT[((l*2+k)*32+i4)*256+o]
        int o = g & 255, i4 = (g >> 8) & 31, k = (g >> 13) & 1, l = g >> 14;
        const float* s = cw + (((size_t)(l * 256 + o) * 128 + i4 * 4) * 2) + k;
        v = make_float4(s[0], s[2], s[4], s[6]);
        dst = ws + OFF_CAUSAL + (size_t)g * 4;
    } else if (g < 409600) {                // condT[(l*16+j4)*256+o]
        int gg = g - 327680;
        int o = gg & 255, j4 = (gg >> 8) & 15, l = gg >> 12;
        const float* s = dw + (size_t)(l * 256 + o) * 64 + j4 * 4;
        v = make_float4(s[0], s[1], s[2], s[3]);
        dst = ws + OFF_COND + (size_t)gg * 4;
    } else if (g < 491520) {                // resT[(l*32+i4)*128+r]
        int gg = g - 409600;
        int r = gg & 127, i4 = (gg >> 7) & 31, l = gg >> 12;
        const float* s = rw + (size_t)(l * 128 + r) * 128 + i4 * 4;
        v = make_float4(s[0], s[1], s[2], s[3]);
        dst = ws + OFF_RES + (size_t)gg * 4;
    } else if (g < 573440) {                // skipT
        int gg = g - 491520;
        int r = gg & 127, i4 = (gg >> 7) & 31, l = gg >> 12;
        const float* s = sw + (size_t)(l * 128 + r) * 128 + i4 * 4;
        v = make_float4(s[0], s[1], s[2], s[3]);
        dst = ws + OFF_SKIP + (size_t)gg * 4;
    } else if (g < 577536) {                // skipcT[i4*128+s]
        int gg = g - 573440;
        int s0 = gg & 127, i4 = gg >> 7;
        const float* s = scw + (size_t)s0 * 128 + i4 * 4;
        v = make_float4(s[0], s[1], s[2], s[3]);
        dst = ws + OFF_SKIPC + (size_t)gg * 4;
    } else if (g < 581632) {                // fcT[i4*128+o]
        int gg = g - 577536;
        int o = gg & 127, i4 = gg >> 7;
        const float* s = fw + (size_t)o * 128 + i4 * 4;
        v = make_float4(s[0], s[1], s[2], s[3]);
        dst = ws + OFF_FC + (size_t)gg * 4;
    } else if (g < 583680) {                // condfT[j4*128+o]
        int gg = g - 581632;
        int o = gg & 127, j4 = gg >> 7;
        const float* s = cfw + (size_t)o * 64 + j4 * 4;
        v = make_float4(s[0], s[1], s[2], s[3]);
        dst = ws + OFF_CONDF + (size_t)gg * 4;
    } else {                                // logitsT[o4*256+q]
        int gg = g - 583680;
        int q = gg & 255, o4 = gg >> 8;
        const float* s = lw + (size_t)q * 128 + o4 * 4;
        v = make_float4(s[0], s[1], s[2], s[3]);
        dst = ws + OFF_LOGITS + (size_t)gg * 4;
    }
    *(float4*)dst = v;
}

// ============================================================
// generator: one block per batch element, full T=512 loop inside
// ============================================================
__global__ __launch_bounds__(NTHR, 2) void wn_gen(
    const float* __restrict__ enc,      // (8,64,8)
    const float* __restrict__ first_w,  // (128,1,2)
    const float* __restrict__ first_b,  // (128)
    const float* __restrict__ causal_b, // (20,256)
    const float* __restrict__ cond_b,   // (20,256)
    const float* __restrict__ res_b,    // (20,128)
    const float* __restrict__ skip_b,   // (20,128)
    const float* __restrict__ skipc_b,  // (128)
    const float* __restrict__ fc_b,     // (128)
    const float* __restrict__ condf_b,  // (128)
    const float* __restrict__ logits_b, // (256)
    float* __restrict__ ws,
    float* __restrict__ out)            // [0:4096) samples(float), then logits
{
    const int tid = threadIdx.x;
    const int b = blockIdx.x;
    float* buf = ws + OFF_BUF + (size_t)b * BUF_PER_BATCH;

    __shared__ float s_condz[LL * 256];   // per-chunk: c@cond^T + cond_b + causal_b
    __shared__ float s_sfc[128];          // per-chunk: c@condf^T + condf_b + fc_b
    __shared__ float s_c[64];
    __shared__ float s_prev[128];
    __shared__ float s_res[128];
    __shared__ float s_skip[128];
    __shared__ float s_h[128];
    __shared__ float s_zp[2][256];
    __shared__ float s_rp[2][128];
    __shared__ float s_sp[2][128];
    __shared__ float s_av[256];
    __shared__ int   s_ai[256];
    __shared__ float s_x, s_prev0;

    // zero this batch's dilation buffers (ws is poisoned each launch)
    for (int i = tid; i < (int)(BUF_PER_BATCH / 4); i += NTHR)
        ((float4*)buf)[i] = make_float4(0.f, 0.f, 0.f, 0.f);
    if (tid == 0) { s_x = 128.f / 255.f - 0.5f; s_prev0 = 0.f; }
    __syncthreads();

    for (int t = 0; t < TT; ++t) {
        // ---- per-chunk precompute (c changes every 64 steps) ----
        if ((t & 63) == 0) {
            if (tid < 64) s_c[tid] = enc[(size_t)b * 512 + tid * 8 + (t >> 6)];
            __syncthreads();
            for (int m = tid; m < LL * 256; m += NTHR) {
                int l = m >> 8, o = m & 255;
                float acc = causal_b[m] + cond_b[m];
                const float4* wp = (const float4*)(ws + OFF_COND) + (size_t)(l * 16) * 256 + o;
                #pragma unroll
                for (int j4 = 0; j4 < 16; ++j4) {
                    float4 w = wp[(size_t)j4 * 256];
                    const float* cc = &s_c[j4 * 4];
                    acc += w.x * cc[0] + w.y * cc[1] + w.z * cc[2] + w.w * cc[3];
                }
                s_condz[m] = acc;
            }
            if (tid < 128) {
                float acc = fc_b[tid] + condf_b[tid];
                const float4* wp = (const float4*)(ws + OFF_CONDF) + tid;
                #pragma unroll
                for (int j4 = 0; j4 < 16; ++j4) {
                    float4 w = wp[(size_t)j4 * 128];
                    const float* cc = &s_c[j4 * 4];
                    acc += w.x * cc[0] + w.y * cc[1] + w.z * cc[2] + w.w * cc[3];
                }
                s_sfc[tid] = acc;
            }
            __syncthreads();
        }

        // prefetch layer-0 prev (slot idx is always 0 for d=1)
        float pfv = 0.f;
        if (tid < 128) pfv = buf[tid];

        // ---- first layer ----
        float xv = s_x;
        if (tid < 128) {
            float p0 = s_prev0;
            s_res[tid] = p0 * first_w[2 * tid] + xv * first_w[2 * tid + 1] + first_b[tid];
        }
        __syncthreads();
        if (tid == 0) s_prev0 = xv;

        // skip init partials: skip = res @ skipc^T + skipc_b  (split K in halves)
        if (tid < 256) {
            int s0 = tid & 127, half = tid >> 7;
            float acc = half ? 0.f : skipc_b[s0];
            const float4* wp = (const float4*)(ws + OFF_SKIPC) + (size_t)(half * 16) * 128 + s0;
            #pragma unroll
            for (int i4 = 0; i4 < 16; ++i4) {
                float4 w = wp[(size_t)i4 * 128];
                const float* rr = &s_res[(half * 16 + i4) * 4];
                acc += w.x * rr[0] + w.y * rr[1] + w.z * rr[2] + w.w * rr[3];
            }
            s_sp[half][s0] = acc;
        }
        __syncthreads();

        // ---- layer loop ----
        for (int l = 0; l < LL; ++l) {
            // PhaseA: combine previous partials, write buf slot, publish prev
            if (tid < 128) {
                if (l == 0) {
                    s_skip[tid] = s_sp[0][tid] + s_sp[1][tid];
                } else {
                    s_res[tid] += s_rp[0][tid] + s_rp[1][tid];
                    s_skip[tid] += s_sp[0][tid] + s_sp[1][tid];
                }
                buf[c_layoff[l] + ((t & (c_dil[l] - 1)) << 7) + tid] = s_res[tid];
                s_prev[tid] = pfv;
            }
            // prefetch next layer's prev (latency hidden under z/h/res phases)
            float pfn = 0.f;
            if (l < LL - 1 && tid < 128)
                pfn = buf[c_layoff[l + 1] + ((t & (c_dil[l + 1] - 1)) << 7) + tid];
            __syncthreads();

            // PhaseB: z partials. half0: prev @ W0^T ; half1: res @ W1^T
            {
                int o = tid & 255, half = tid >> 8;
                const float* src = half ? s_res : s_prev;
                const float4* wp = (const float4*)(ws + OFF_CAUSAL) +
                                   (size_t)((l * 2 + half) * 32) * 256 + o;
                float acc = 0.f;
                #pragma unroll
                for (int i4 = 0; i4 < 32; ++i4) {
                    float4 w = wp[(size_t)i4 * 256];
                    const float* rr = &src[i4 * 4];
                    acc += w.x * rr[0] + w.y * rr[1] + w.z * rr[2] + w.w * rr[3];
                }
                s_zp[half][o] = acc;
            }
            __syncthreads();

            // PhaseC: h = sigmoid(gate)*tanh(out)
            if (tid < 128) {
                float g = s_zp[0][tid] + s_zp[1][tid] + s_condz[l * 256 + tid];
                float oo = s_zp[0][tid + 128] + s_zp[1][tid + 128] + s_condz[l * 256 + tid + 128];
                s_h[tid] = (1.f / (1.f + expf(-g))) * tanhf(oo);
            }
            __syncthreads();

            // PhaseD: res/skip update partials (4 quarter-groups of 128 threads)
            {
                int r = tid & 127;
                int q = tid >> 7;          // 0..3
                int half = q & 1;
                int isSkip = q >> 1;
                const float* base = ws + (isSkip ? OFF_SKIP : OFF_RES);
                const float4* wp = (const float4*)base + (size_t)(l * 32 + half * 16) * 128 + r;
                float acc = half ? 0.f
                                 : (isSkip ? skip_b[l * 128 + r] : res_b[l * 128 + r]);
                #pragma unroll
                for (int i4 = 0; i4 < 16; ++i4) {
                    float4 w = wp[(size_t)i4 * 128];
                    const float* hh = &s_h[(half * 16 + i4) * 4];
                    acc += w.x * hh[0] + w.y * hh[1] + w.z * hh[2] + w.w * hh[3];
                }
                if (isSkip) s_sp[half][r] = acc; else s_rp[half][r] = acc;
            }
            __syncthreads();
            pfv = pfn;
        }

        // ---- final head ----
        // combine last skip partials + relu  (res no longer needed)
        if (tid < 128) {
            float sk = s_skip[tid] + s_sp[0][tid] + s_sp[1][tid];
            s_prev[tid] = fmaxf(sk, 0.f);   // reuse s_prev = relu(skip)
        }
        __syncthreads();
        // s = relu(skip) @ fc^T + (fc_b + c@condf^T + condf_b)
        if (tid < 256) {
            int o = tid & 127, half = tid >> 7;
            float acc = half ? 0.f : s_sfc[o];
            const float4* wp = (const float4*)(ws + OFF_FC) + (size_t)(half * 16) * 128 + o;
            #pragma unroll
            for (int i4 = 0; i4 < 16; ++i4) {
                float4 w = wp[(size_t)i4 * 128];
                const float* rr = &s_prev[(half * 16 + i4) * 4];
                acc += w.x * rr[0] + w.y * rr[1] + w.z * rr[2] + w.w * rr[3];
            }
            s_sp[half][o] = acc;
        }
        __syncthreads();
        if (tid < 128) s_h[tid] = fmaxf(s_sp[0][tid] + s_sp[1][tid], 0.f);
        __syncthreads();
        // logits
        if (tid < 256) {
            float acc = logits_b[tid];
            const float4* wp = (const float4*)(ws + OFF_LOGITS) + tid;
            #pragma unroll
            for (int o4 = 0; o4 < 32; ++o4) {
                float4 w = wp[(size_t)o4 * 256];
                const float* hh = &s_h[o4 * 4];
                acc += w.x * hh[0] + w.y * hh[1] + w.z * hh[2] + w.w * hh[3];
            }
            out[4096 + ((size_t)(t * BB + b)) * 256 + tid] = acc;
            s_av[tid] = acc;
            s_ai[tid] = tid;
        }
        __syncthreads();
        // argmax with first-index tie-break (matches jnp.argmax)
        for (int str = 128; str >= 1; str >>= 1) {
            if (tid < str) {
                float av = s_av[tid], bv = s_av[tid + str];
                int ai = s_ai[tid], bi = s_ai[tid + str];
                if (bv > av || (bv == av && bi < ai)) { s_av[tid] = bv; s_ai[tid] = bi; }
            }
            __syncthreads();
        }
        if (tid == 0) {
            int samp = s_ai[0];
            out[t * BB + b] = (float)samp;
            s_x = (float)samp * (1.f / 255.f) - 0.5f;
        }
        __syncthreads();
    }
}

// ============================================================
extern "C" void kernel_launch(void* const* d_in, const int* in_sizes, int n_in,
                              void* d_out, int out_size, void* d_ws, size_t ws_size,
                              hipStream_t stream) {
    const float* enc      = (const float*)d_in[0];
    const float* first_w  = (const float*)d_in[1];
    const float* first_b  = (const float*)d_in[2];
    const float* causal_w = (const float*)d_in[3];
    const float* causal_b = (const float*)d_in[4];
    const float* cond_w   = (const float*)d_in[5];
    const float* cond_b   = (const float*)d_in[6];
    const float* res_w    = (const float*)d_in[7];
    const float* res_b    = (const float*)d_in[8];
    const float* skip_w   = (const float*)d_in[9];
    const float* skip_b   = (const float*)d_in[10];
    const float* skipc_w  = (const float*)d_in[11];
    const float* skipc_b  = (const float*)d_in[12];
    const float* fc_w     = (const float*)d_in[13];
    const float* fc_b     = (const float*)d_in[14];
    const float* condf_w  = (const float*)d_in[15];
    const float* condf_b  = (const float*)d_in[16];
    const float* logits_w = (const float*)d_in[17];
    const float* logits_b = (const float*)d_in[18];

    float* ws  = (float*)d_ws;
    float* out = (float*)d_out;

    wn_prep<<<2312, 256, 0, stream>>>(causal_w, cond_w, res_w, skip_w,
                                      skipc_w, fc_w, condf_w, logits_w, ws);
    wn_gen<<<BB, NTHR, 0, stream>>>(enc, first_w, first_b, causal_b, cond_b,
                                    res_b, skip_b, skipc_b, fc_b, condf_b,
                                    logits_b, ws, out);
}

// Round 2
// 136659.583 us; speedup vs baseline: 1.1076x; 1.1076x over previous
//
#include <hip/hip_runtime.h>
#include <hip/hip_bf16.h>
#include <math.h>

// ---------------- problem constants ----------------
#define BB 8
#define CC 64
#define TE 8
#define TT 512
#define RR 128
#define SS 128
#define QQ 256
#define LL 20
#define NTHR 512
#define NBAR (3 * TT)

// dilations are powers of two -> use masks
__constant__ int c_dil[LL] = {1,2,4,8,16,32,64,128,256,512,
                              1,2,4,8,16,32,64,128,256,512};
// per-layer float offset into one batch's dilation-buffer region (d*128 cumsum)
__constant__ int c_layoff[LL] = {0,128,384,896,1920,3968,8064,16256,32640,65408,
                                 130944,131072,131328,131840,132864,134912,139008,147200,163584,196352};

// ---------------- workspace layout (in floats) ----------------
constexpr size_t BUF_PER_BATCH = 261888;           // 2046*128
constexpr size_t OFF_BUF    = 0;
constexpr size_t OFF_CAUSAL = 2095104;             // 8*261888
constexpr size_t OFF_RES    = OFF_CAUSAL + 1310720;
constexpr size_t OFF_SKIP   = OFF_RES    + 327680;
constexpr size_t OFF_COND   = OFF_SKIP   + 327680;
constexpr size_t OFF_SKIPC  = OFF_COND   + 327680;
constexpr size_t OFF_FC     = OFF_SKIPC  + 16384;
constexpr size_t OFF_CONDF  = OFF_FC     + 16384;
constexpr size_t OFF_LOGITS = OFF_CONDF  + 8192;
constexpr size_t OFF_FLAGS  = OFF_LOGITS + 32768;  // NBAR ints (barrier counters)
// end ~ 17.86 MB

// ============================================================
// prep: transpose all weights into [kgroup][out][4] float4 layout + zero flags
// ============================================================
__global__ void wn_prep(const float* __restrict__ cw,   // causal_w (20,256,128,2)
                        const float* __restrict__ dw,   // cond_w   (20,256,64)
                        const float* __restrict__ rw,   // res_w    (20,128,128)
                        const float* __restrict__ sw,   // skip_w   (20,128,128)
                        const float* __restrict__ scw,  // skipc_w  (128,128)
                        const float* __restrict__ fw,   // fc_w     (128,128)
                        const float* __restrict__ cfw,  // condf_w  (128,64)
                        const float* __restrict__ lw,   // logits_w (256,128)
                        float* __restrict__ ws)
{
    int g = blockIdx.x * blockDim.x + threadIdx.x;
    if (g < NBAR) ((int*)(ws + OFF_FLAGS))[g] = 0;   // barrier counters
    if (g >= 591872) return;
    float4 v;
    float* dst;
    if (g < 327680) {                       // causalT[((l*2+k)*32+i4)*256+o]
        int o = g & 255, i4 = (g >> 8) & 31, k = (g >> 13) & 1, l = g >> 14;
        const float* s = cw + (((size_t)(l * 256 + o) * 128 + i4 * 4) * 2) + k;
        v = make_float4(s[0], s[2], s[4], s[6]);
        dst = ws + OFF_CAUSAL + (size_t)g * 4;
    } else if (g < 409600) {                // condT[(l*16+j4)*256+o]
        int gg = g - 327680;
        int o = gg & 255, j4 = (gg >> 8) & 15, l = gg >> 12;
        const float* s = dw + (size_t)(l * 256 + o) * 64 + j4 * 4;
        v = make_float4(s[0], s[1], s[2], s[3]);
        dst = ws + OFF_COND + (size_t)gg * 4;
    } else if (g < 491520) {                // resT[(l*32+i4)*128+r]
        int gg = g - 409600;
        int r = gg & 127, i4 = (gg >> 7) & 31, l = gg >> 12;
        const float* s = rw + (size_t)(l * 128 + r) * 128 + i4 * 4;
        v = make_float4(s[0], s[1], s[2], s[3]);
        dst = ws + OFF_RES + (size_t)gg * 4;
    } else if (g < 573440) {                // skipT
        int gg = g - 491520;
        int r = gg & 127, i4 = (gg >> 7) & 31, l = gg >> 12;
        const float* s = sw + (size_t)(l * 128 + r) * 128 + i4 * 4;
        v = make_float4(s[0], s[1], s[2], s[3]);
        dst = ws + OFF_SKIP + (size_t)gg * 4;
    } else if (g < 577536) {                // skipcT[i4*128+s]
        int gg = g - 573440;
        int s0 = gg & 127, i4 = gg >> 7;
        const float* s = scw + (size_t)s0 * 128 + i4 * 4;
        v = make_float4(s[0], s[1], s[2], s[3]);
        dst = ws + OFF_SKIPC + (size_t)gg * 4;
    } else if (g < 581632) {                // fcT[i4*128+o]
        int gg = g - 577536;
        int o = gg & 127, i4 = gg >> 7;
        const float* s = fw + (size_t)o * 128 + i4 * 4;
        v = make_float4(s[0], s[1], s[2], s[3]);
        dst = ws + OFF_FC + (size_t)gg * 4;
    } else if (g < 583680) {                // condfT[j4*128+o]
        int gg = g - 581632;
        int o = gg & 127, j4 = gg >> 7;
        const float* s = cfw + (size_t)o * 64 + j4 * 4;
        v = make_float4(s[0], s[1], s[2], s[3]);
        dst = ws + OFF_CONDF + (size_t)gg * 4;
    } else {                                // logitsT[o4*256+q]
        int gg = g - 583680;
        int q = gg & 255, o4 = gg >> 8;
        const float* s = lw + (size_t)q * 128 + o4 * 4;
        v = make_float4(s[0], s[1], s[2], s[3]);
        dst = ws + OFF_LOGITS + (size_t)gg * 4;
    }
    *(float4*)dst = v;
}

// cross-block barrier among the 8 working blocks (all co-resident by
// construction: 57 blocks on 256 CUs). Counter used once per launch.
__device__ __forceinline__ void xbar(int* flags, int id, int tid) {
    __syncthreads();
    if (tid == 0) {
        __hip_atomic_fetch_add(&flags[id], 1, __ATOMIC_RELAXED, __HIP_MEMORY_SCOPE_AGENT);
        while (__hip_atomic_load(&flags[id], __ATOMIC_RELAXED, __HIP_MEMORY_SCOPE_AGENT) < BB)
            __builtin_amdgcn_s_sleep(8);
    }
    __syncthreads();
}

// ============================================================
// generator: one block per batch; work blocks at blockIdx%8==0 so all land
// on ONE XCD (round-robin heuristic) and share its L2 for weight streams.
// ============================================================
__global__ __launch_bounds__(NTHR, 2) void wn_gen(
    const float* __restrict__ enc,      // (8,64,8)
    const float* __restrict__ first_w,  // (128,1,2)
    const float* __restrict__ first_b,  // (128)
    const float* __restrict__ causal_b, // (20,256)
    const float* __restrict__ cond_b,   // (20,256)
    const float* __restrict__ res_b,    // (20,128)
    const float* __restrict__ skip_b,   // (20,128)
    const float* __restrict__ skipc_b,  // (128)
    const float* __restrict__ fc_b,     // (128)
    const float* __restrict__ condf_b,  // (128)
    const float* __restrict__ logits_b, // (256)
    float* __restrict__ ws,
    float* __restrict__ out)            // [0:4096) samples(float), then logits
{
    if (blockIdx.x & 7) return;         // only blockIdx%8==0 works (same XCD)
    const int tid = threadIdx.x;
    const int b = blockIdx.x >> 3;
    float* buf = ws + OFF_BUF + (size_t)b * BUF_PER_BATCH;
    int* flags = (int*)(ws + OFF_FLAGS);

    __shared__ float s_condz[LL * 256];
    __shared__ float s_sfc[128];
    __shared__ float s_c[64];
    __shared__ float s_prev[128];
    __shared__ float s_res[128];
    __shared__ float s_skip[128];
    __shared__ float s_h[128];
    __shared__ float s_zp[2][256];
    __shared__ float s_rp[2][128];
    __shared__ float s_sp[2][128];
    __shared__ float s_av[256];
    __shared__ int   s_ai[256];
    __shared__ float s_resb[LL * 128];
    __shared__ float s_skipb[LL * 128];
    __shared__ float s_logb[256];
    __shared__ float s_x, s_prev0;

    // zero this batch's dilation buffers (ws is poisoned each launch)
    for (int i = tid; i < (int)(BUF_PER_BATCH / 4); i += NTHR)
        ((float4*)buf)[i] = make_float4(0.f, 0.f, 0.f, 0.f);
    // hoist per-layer biases into LDS (kills per-layer global bias reads)
    for (int i = tid; i < LL * 128; i += NTHR) {
        s_resb[i] = res_b[i];
        s_skipb[i] = skip_b[i];
    }
    if (tid < 256) s_logb[tid] = logits_b[tid];
    if (tid == 0) { s_x = 128.f / 255.f - 0.5f; s_prev0 = 0.f; }
    __syncthreads();

    for (int t = 0; t < TT; ++t) {
        // ---- per-chunk precompute (c changes every 64 steps) ----
        if ((t & 63) == 0) {
            if (tid < 64) s_c[tid] = enc[(size_t)b * 512 + tid * 8 + (t >> 6)];
            __syncthreads();
            for (int m = tid; m < LL * 256; m += NTHR) {
                int l = m >> 8, o = m & 255;
                float acc = causal_b[m] + cond_b[m];
                const float4* wp = (const float4*)(ws + OFF_COND) + (size_t)(l * 16) * 256 + o;
                #pragma unroll
                for (int j4 = 0; j4 < 16; ++j4) {
                    float4 w = wp[(size_t)j4 * 256];
                    const float* cc = &s_c[j4 * 4];
                    acc += w.x * cc[0] + w.y * cc[1] + w.z * cc[2] + w.w * cc[3];
                }
                s_condz[m] = acc;
            }
            if (tid < 128) {
                float acc = fc_b[tid] + condf_b[tid];
                const float4* wp = (const float4*)(ws + OFF_CONDF) + tid;
                #pragma unroll
                for (int j4 = 0; j4 < 16; ++j4) {
                    float4 w = wp[(size_t)j4 * 128];
                    const float* cc = &s_c[j4 * 4];
                    acc += w.x * cc[0] + w.y * cc[1] + w.z * cc[2] + w.w * cc[3];
                }
                s_sfc[tid] = acc;
            }
            __syncthreads();
        }

        // prefetch layer-0 prev (d=1, slot 0; zero until t>=1)
        float pfv = 0.f;
        if (tid < 128 && t >= 1) pfv = buf[tid];

        // ---- first layer ----
        float xv = s_x;
        if (tid < 128) {
            float p0 = s_prev0;
            s_res[tid] = p0 * first_w[2 * tid] + xv * first_w[2 * tid + 1] + first_b[tid];
        }
        __syncthreads();
        if (tid == 0) s_prev0 = xv;

        // skip init partials: skip = res @ skipc^T + skipc_b
        if (tid < 256) {
            int s0 = tid & 127, half = tid >> 7;
            float acc = half ? 0.f : skipc_b[s0];
            const float4* wp = (const float4*)(ws + OFF_SKIPC) + (size_t)(half * 16) * 128 + s0;
            #pragma unroll
            for (int i4 = 0; i4 < 16; ++i4) {
                float4 w = wp[(size_t)i4 * 128];
                const float* rr = &s_res[(half * 16 + i4) * 4];
                acc += w.x * rr[0] + w.y * rr[1] + w.z * rr[2] + w.w * rr[3];
            }
            s_sp[half][s0] = acc;
        }
        __syncthreads();

        // ---- layer loop ----
        for (int l = 0; l < LL; ++l) {
            if (l == 7)  xbar(flags, 3 * t + 0, tid);   // bound inter-block drift
            if (l == 14) xbar(flags, 3 * t + 1, tid);   // to < L2 capacity window

            // PhaseA: combine previous partials, write buf slot, publish prev
            if (tid < 128) {
                if (l == 0) {
                    s_skip[tid] = s_sp[0][tid] + s_sp[1][tid];
                } else {
                    s_res[tid] += s_rp[0][tid] + s_rp[1][tid];
                    s_skip[tid] += s_sp[0][tid] + s_sp[1][tid];
                }
                buf[c_layoff[l] + ((t & (c_dil[l] - 1)) << 7) + tid] = s_res[tid];
                s_prev[tid] = pfv;
            }
            // prefetch next layer's prev (zero until t >= d)
            float pfn = 0.f;
            if (l < LL - 1 && tid < 128 && t >= c_dil[l + 1])
                pfn = buf[c_layoff[l + 1] + ((t & (c_dil[l + 1] - 1)) << 7) + tid];
            __syncthreads();

            // PhaseB: z partials. half0: prev @ W0^T (skip while prev==0);
            //         half1: res @ W1^T
            {
                int o = tid & 255, half = tid >> 8;   // wave-uniform
                float acc = 0.f;
                if (half || t >= c_dil[l]) {
                    const float* src = half ? s_res : s_prev;
                    const float4* wp = (const float4*)(ws + OFF_CAUSAL) +
                                       (size_t)((l * 2 + half) * 32) * 256 + o;
                    #pragma unroll
                    for (int i4 = 0; i4 < 32; ++i4) {
                        float4 w = wp[(size_t)i4 * 256];
                        const float* rr = &src[i4 * 4];
                        acc += w.x * rr[0] + w.y * rr[1] + w.z * rr[2] + w.w * rr[3];
                    }
                }
                s_zp[half][o] = acc;
            }
            __syncthreads();

            // PhaseC: h = sigmoid(gate)*tanh(out)
            if (tid < 128) {
                float g = s_zp[0][tid] + s_zp[1][tid] + s_condz[l * 256 + tid];
                float oo = s_zp[0][tid + 128] + s_zp[1][tid + 128] + s_condz[l * 256 + tid + 128];
                s_h[tid] = (1.f / (1.f + expf(-g))) * tanhf(oo);
            }
            __syncthreads();

            // PhaseD: res/skip update partials
            {
                int r = tid & 127;
                int q = tid >> 7;          // 0..3
                int half = q & 1;
                int isSkip = q >> 1;
                const float* base = ws + (isSkip ? OFF_SKIP : OFF_RES);
                const float4* wp = (const float4*)base + (size_t)(l * 32 + half * 16) * 128 + r;
                float acc = half ? 0.f
                                 : (isSkip ? s_skipb[l * 128 + r] : s_resb[l * 128 + r]);
                #pragma unroll
                for (int i4 = 0; i4 < 16; ++i4) {
                    float4 w = wp[(size_t)i4 * 128];
                    const float* hh = &s_h[(half * 16 + i4) * 4];
                    acc += w.x * hh[0] + w.y * hh[1] + w.z * hh[2] + w.w * hh[3];
                }
                if (isSkip) s_sp[half][r] = acc; else s_rp[half][r] = acc;
            }
            __syncthreads();
            pfv = pfn;
        }

        // ---- final head ----
        if (tid < 128) {
            float sk = s_skip[tid] + s_sp[0][tid] + s_sp[1][tid];
            s_prev[tid] = fmaxf(sk, 0.f);   // reuse s_prev = relu(skip)
        }
        __syncthreads();
        if (tid < 256) {
            int o = tid & 127, half = tid >> 7;
            float acc = half ? 0.f : s_sfc[o];
            const float4* wp = (const float4*)(ws + OFF_FC) + (size_t)(half * 16) * 128 + o;
            #pragma unroll
            for (int i4 = 0; i4 < 16; ++i4) {
                float4 w = wp[(size_t)i4 * 128];
                const float* rr = &s_prev[(half * 16 + i4) * 4];
                acc += w.x * rr[0] + w.y * rr[1] + w.z * rr[2] + w.w * rr[3];
            }
            s_sp[half][o] = acc;
        }
        __syncthreads();
        if (tid < 128) s_h[tid] = fmaxf(s_sp[0][tid] + s_sp[1][tid], 0.f);
        __syncthreads();
        // logits
        if (tid < 256) {
            float acc = s_logb[tid];
            const float4* wp = (const float4*)(ws + OFF_LOGITS) + tid;
            #pragma unroll
            for (int o4 = 0; o4 < 32; ++o4) {
                float4 w = wp[(size_t)o4 * 256];
                const float* hh = &s_h[o4 * 4];
                acc += w.x * hh[0] + w.y * hh[1] + w.z * hh[2] + w.w * hh[3];
            }
            out[4096 + ((size_t)(t * BB + b)) * 256 + tid] = acc;
            s_av[tid] = acc;
            s_ai[tid] = tid;
        }
        __syncthreads();
        // argmax with first-index tie-break (matches jnp.argmax)
        for (int str = 128; str >= 1; str >>= 1) {
            if (tid < str) {
                float av = s_av[tid], bv = s_av[tid + str];
                int ai = s_ai[tid], bi = s_ai[tid + str];
                if (bv > av || (bv == av && bi < ai)) { s_av[tid] = bv; s_ai[tid] = bi; }
            }
            __syncthreads();
        }
        if (tid == 0) {
            int samp = s_ai[0];
            out[t * BB + b] = (float)samp;
            s_x = (float)samp * (1.f / 255.f) - 0.5f;
        }
        xbar(flags, 3 * t + 2, tid);       // end-of-step rendezvous
    }
}

// ============================================================
extern "C" void kernel_launch(void* const* d_in, const int* in_sizes, int n_in,
                              void* d_out, int out_size, void* d_ws, size_t ws_size,
                              hipStream_t stream) {
    const float* enc      = (const float*)d_in[0];
    const float* first_w  = (const float*)d_in[1];
    const float* first_b  = (const float*)d_in[2];
    const float* causal_w = (const float*)d_in[3];
    const float* causal_b = (const float*)d_in[4];
    const float* cond_w   = (const float*)d_in[5];
    const float* cond_b   = (const float*)d_in[6];
    const float* res_w    = (const float*)d_in[7];
    const float* res_b    = (const float*)d_in[8];
    const float* skip_w   = (const float*)d_in[9];
    const float* skip_b   = (const float*)d_in[10];
    const float* skipc_w  = (const float*)d_in[11];
    const float* skipc_b  = (const float*)d_in[12];
    const float* fc_w     = (const float*)d_in[13];
    const float* fc_b     = (const float*)d_in[14];
    const float* condf_w  = (const float*)d_in[15];
    const float* condf_b  = (const float*)d_in[16];
    const float* logits_w = (const float*)d_in[17];
    const float* logits_b = (const float*)d_in[18];

    float* ws  = (float*)d_ws;
    float* out = (float*)d_out;

    wn_prep<<<2312, 256, 0, stream>>>(causal_w, cond_w, res_w, skip_w,
                                      skipc_w, fc_w, condf_w, logits_w, ws);
    // 57 blocks: work blocks at 0,8,...,56 -> same XCD under %8 round-robin
    wn_gen<<<57, NTHR, 0, stream>>>(enc, first_w, first_b, causal_b, cond_b,
                                    res_b, skip_b, skipc_b, fc_b, condf_b,
                                    logits_b, ws, out);
}

// Round 3
// 92066.595 us; speedup vs baseline: 1.6441x; 1.4844x over previous
//
#include <hip/hip_runtime.h>
#include <hip/hip_bf16.h>
#include <math.h>

// ---------------- problem constants ----------------
#define BB 8
#define TT 512
#define LL 20
#define NBLK 64
#define NTHR 256
#define NFLAGS (1 + TT * 42)

__constant__ int c_dil[LL] = {1,2,4,8,16,32,64,128,256,512,
                              1,2,4,8,16,32,64,128,256,512};
// float offsets of dilation buffer per layer (layers 1..19; l=0 handled in LDS)
__constant__ int c_bufoff[LL] = {-1, 0, 2048, 6144, 14336, 30720, 63488, 129024,
                                 260096, 522240, 1046528, 1047552, 1049600,
                                 1053696, 1061888, 1078272, 1111040, 1176576,
                                 1307648, 1569792};

// ---------------- workspace layout (floats) ----------------
constexpr size_t OFF_BUF   = 0;          // 2045 slots * 1024 = 2,094,080
constexpr size_t OFF_HG    = 2094080;    // h gather  (8*128)
constexpr size_t OFF_RESG  = 2095104;    // res gather
constexpr size_t OFF_SKIPG = 2096128;    // skip gather
constexpr size_t OFF_SG    = 2097152;    // s gather
constexpr size_t OFF_LGG   = 2098176;    // logits gather (8*256)
constexpr size_t OFF_FLAGS = 2100224;    // NFLAGS ints

// ---------------- LDS pool offsets (floats) ----------------
#define P_WC     0        // [20][4][256] causal rows (W0|W1)
#define P_WRES   20480    // [20][2][128]
#define P_WSKIP  25600
#define P_WSKIPC 30720    // [2][128]
#define P_WFC    30976
#define P_WLOG   31232    // [4][128]
#define P_WF0    31744    // [128]
#define P_WF1    31872
#define P_FB     32000
#define P_CONDZ  32128    // [20][4][8]
#define P_SFC    32768    // [2][8]
#define P_RESB   32784    // [20][2]
#define P_SKIPB  32824
#define P_LOGB   32864    // [4]
#define P_SKIPCB 32868    // [2] (+2 pad)
#define P_RESF   32872    // [8][132]
#define P_HF     33928    // [8][132]
#define P_RING   34984    // [2][8][132]  (aliased as lgF [8][260] at head)
#define P_RES0   37096    // [2][8][132]
#define P_SZ     39208    // [4][10]
#define P_SKACC  39248    // [2][8]
#define P_XCUR   39264    // [8]
#define P_XPREV  39272
#define P_XNEW   39280
#define P_CF     39288    // [8][66]
#define POOL_FL  39816    // 159,264 bytes

// zero the barrier flags each launch
__global__ void wn_prep(int* __restrict__ flags) {
    int g = blockIdx.x * blockDim.x + threadIdx.x;
    if (g < NFLAGS) flags[g] = 0;
}

__device__ __forceinline__ void gbar(int* flags, int id) {
    __syncthreads();
    if (threadIdx.x == 0) {
        __hip_atomic_fetch_add(&flags[id], 1, __ATOMIC_RELEASE, __HIP_MEMORY_SCOPE_AGENT);
        while (__hip_atomic_load(&flags[id], __ATOMIC_RELAXED, __HIP_MEMORY_SCOPE_AGENT) < NBLK)
            __builtin_amdgcn_s_sleep(1);
        (void)__hip_atomic_load(&flags[id], __ATOMIC_ACQUIRE, __HIP_MEMORY_SCOPE_AGENT);
    }
    __syncthreads();
}

// ============================================================
// 64 persistent blocks; block J owns z-rows {2J,2J+1,128+2J,128+2J+1},
// h/res/skip/s rows {2J,2J+1}, logits rows {4J..4J+3} of EVERY layer,
// weights LDS-resident. All 8 batches processed together (M=8).
// ============================================================
__global__ __launch_bounds__(NTHR, 1) void wn_gen(
    const float* __restrict__ enc,
    const float* __restrict__ first_w,  const float* __restrict__ first_b,
    const float* __restrict__ causal_w, const float* __restrict__ causal_b,
    const float* __restrict__ cond_w,   const float* __restrict__ cond_b,
    const float* __restrict__ res_w,    const float* __restrict__ res_b,
    const float* __restrict__ skip_w,   const float* __restrict__ skip_b,
    const float* __restrict__ skipc_w,  const float* __restrict__ skipc_b,
    const float* __restrict__ fc_w,     const float* __restrict__ fc_b,
    const float* __restrict__ condf_w,  const float* __restrict__ condf_b,
    const float* __restrict__ logits_w, const float* __restrict__ logits_b,
    float* __restrict__ wsf, float* __restrict__ out)
{
    extern __shared__ float pool[];
    const int tid = threadIdx.x;
    const int J = blockIdx.x;
    int* flags = (int*)(wsf + OFF_FLAGS);
    int bid = 0;

    // ---------------- init: load weight slices into LDS ----------------
    for (int m = tid; m < 20480; m += NTHR) {          // causal
        int l = m >> 10, rem = m & 1023, w = rem >> 8, i = rem & 255;
        int grow = (w < 2) ? (2 * J + w) : (128 + 2 * J + (w - 2));
        pool[P_WC + m] = causal_w[((size_t)(l * 256 + grow) * 128 + (i & 127)) * 2 + (i >> 7)];
    }
    for (int m = tid; m < 5120; m += NTHR) {           // res_w / skip_w
        int l = m >> 8, r = (m >> 7) & 1, i = m & 127;
        pool[P_WRES + m]  = res_w[(size_t)(l * 128 + 2 * J + r) * 128 + i];
        pool[P_WSKIP + m] = skip_w[(size_t)(l * 128 + 2 * J + r) * 128 + i];
    }
    if (tid < 256) {                                   // skipc / fc rows
        int r = tid >> 7, i = tid & 127;
        pool[P_WSKIPC + tid] = skipc_w[(size_t)(2 * J + r) * 128 + i];
        pool[P_WFC + tid]    = fc_w[(size_t)(2 * J + r) * 128 + i];
    }
    for (int m = tid; m < 512; m += NTHR) {            // logits rows
        int w = m >> 7, i = m & 127;
        pool[P_WLOG + m] = logits_w[(size_t)(4 * J + w) * 128 + i];
    }
    if (tid < 128) {
        pool[P_WF0 + tid] = first_w[2 * tid];
        pool[P_WF1 + tid] = first_w[2 * tid + 1];
        pool[P_FB + tid]  = first_b[tid];
    }
    if (tid < 40) {
        int l = tid >> 1, r = tid & 1;
        pool[P_RESB + tid]  = res_b[l * 128 + 2 * J + r];
        pool[P_SKIPB + tid] = skip_b[l * 128 + 2 * J + r];
    }
    if (tid < 4) pool[P_LOGB + tid] = logits_b[4 * J + tid];
    if (tid < 2) pool[P_SKIPCB + tid] = skipc_b[2 * J + tid];
    for (int m = tid; m < 2112; m += NTHR) pool[P_RES0 + m] = 0.f;
    if (tid < 8) { pool[P_XCUR + tid] = 128.f / 255.f - 0.5f; pool[P_XPREV + tid] = 0.f; }
    // zero this block's share of the dilation buffers (32720 floats each)
    {
        float4* bz = (float4*)(wsf + OFF_BUF + (size_t)J * 32720);
        for (int m = tid; m < 8180; m += NTHR) bz[m] = make_float4(0.f, 0.f, 0.f, 0.f);
    }
    gbar(flags, bid++);   // init rendezvous (buffers zeroed, weights loaded)

    // ---------------- generation loop ----------------
    for (int t = 0; t < TT; ++t) {
        // ---- per-chunk (every 64 steps): condz and sfc slices ----
        if ((t & 63) == 0) {
            int te = t >> 6;
            for (int m = tid; m < 512; m += NTHR) {
                int b = m >> 6, j = m & 63;
                pool[P_CF + b * 66 + j] = enc[(size_t)b * 512 + j * 8 + te];
            }
            __syncthreads();
            for (int m = tid; m < 640; m += NTHR) {
                int l = m >> 5, rem = m & 31, w = rem >> 3, b = rem & 7;
                int grow = (w < 2) ? (2 * J + w) : (128 + 2 * J + (w - 2));
                float acc = causal_b[l * 256 + grow] + cond_b[l * 256 + grow];
                const float* cw = cond_w + (size_t)(l * 256 + grow) * 64;
                const float* cf = pool + P_CF + b * 66;
                for (int j = 0; j < 64; ++j) acc += cw[j] * cf[j];
                pool[P_CONDZ + l * 32 + w * 8 + b] = acc;
            }
            if (tid < 16) {
                int r = tid >> 3, b = tid & 7, row = 2 * J + r;
                float acc = fc_b[row] + condf_b[row];
                const float* cw = condf_w + (size_t)row * 64;
                const float* cf = pool + P_CF + b * 66;
                for (int j = 0; j < 64; ++j) acc += cw[j] * cf[j];
                pool[P_SFC + r * 8 + b] = acc;
            }
            __syncthreads();
        }

        const int cur = t & 1;
        // ---- step start: res_0 (full, local), skip init slice, prefetch prev_1
        for (int m = tid; m < 1024; m += NTHR) {
            int b = m >> 7, r = m & 127;
            pool[P_RES0 + cur * 1056 + b * 132 + r] =
                pool[P_XPREV + b] * pool[P_WF0 + r] + pool[P_XCUR + b] * pool[P_WF1 + r] + pool[P_FB + r];
        }
        {   // prefetch prev_1 (layer 1, d=2) into ring[1]
            int m4 = tid * 4, b = m4 >> 7, c = m4 & 127;
            float4 v = *(const float4*)(wsf + OFF_BUF + c_bufoff[1] + ((t & 1) << 10) + m4);
            *(float4*)(pool + P_RING + 1 * 1056 + b * 132 + c) = v;
        }
        __syncthreads();
        {   // skip = res0 @ skipc^T + skipc_b  (slice rows 2J..2J+1)
            int p = tid >> 4, k = tid & 15, r = p >> 3, b = p & 7;
            float acc = 0.f;
            #pragma unroll
            for (int i = 0; i < 8; ++i) {
                int jj = (i + k) & 7;
                acc += pool[P_WSKIPC + r * 128 + k * 8 + jj] *
                       pool[P_RES0 + cur * 1056 + b * 132 + k * 8 + jj];
            }
            acc += __shfl_xor(acc, 1); acc += __shfl_xor(acc, 2);
            acc += __shfl_xor(acc, 4); acc += __shfl_xor(acc, 8);
            if (k == 0) pool[P_SKACC + r * 8 + b] = acc + pool[P_SKIPCB + r];
        }
        __syncthreads();

        // ---- layer loop ----
        for (int l = 0; l < LL; ++l) {
            // Phase A: stage res gather + prefetch next prev; compute z,h slice
            {
                int m4 = tid * 4, b = m4 >> 7, c = m4 & 127;
                if (l >= 1) {
                    float4 v = *(const float4*)(wsf + OFF_RESG + m4);
                    *(float4*)(pool + P_RESF + b * 132 + c) = v;
                }
                if (l >= 1 && l <= 18) {
                    int d = c_dil[l + 1];
                    float4 v = *(const float4*)(wsf + OFF_BUF + c_bufoff[l + 1] +
                                                ((size_t)(t & (d - 1)) << 10) + m4);
                    *(float4*)(pool + P_RING + ((l + 1) & 1) * 1056 + b * 132 + c) = v;
                }
            }
            __syncthreads();
            {
                int w = tid >> 6, lane = tid & 63, b = lane >> 3, k = lane & 7;
                const float* wrow = pool + P_WC + l * 1024 + w * 256 + ((k >= 4) ? 128 : 0);
                int off = (k & 3) * 32;
                const float* act;
                if (k < 4) act = (l == 0) ? (pool + P_RES0 + (cur ^ 1) * 1056 + b * 132)
                                          : (pool + P_RING + (l & 1) * 1056 + b * 132);
                else       act = (l == 0) ? (pool + P_RES0 + cur * 1056 + b * 132)
                                          : (pool + P_RESF + b * 132);
                float acc = 0.f;
                #pragma unroll
                for (int i = 0; i < 32; ++i) {
                    int jj = (i + 5 * k) & 31;
                    acc += wrow[off + jj] * act[off + jj];
                }
                acc += __shfl_xor(acc, 1); acc += __shfl_xor(acc, 2); acc += __shfl_xor(acc, 4);
                if (k == 0) pool[P_SZ + w * 10 + b] = acc;
            }
            __syncthreads();
            if (tid < 16) {
                int r = tid & 1, b = tid >> 1;
                float g = pool[P_SZ + r * 10 + b]       + pool[P_CONDZ + l * 32 + r * 8 + b];
                float o = pool[P_SZ + (2 + r) * 10 + b] + pool[P_CONDZ + l * 32 + (2 + r) * 8 + b];
                float hv = (1.f / (1.f + expf(-g))) * tanhf(o);
                wsf[OFF_HG + b * 128 + 2 * J + r] = hv;
            }
            gbar(flags, bid++);

            // Phase B: stage full h; res/skip slice updates; publish res
            {
                int m4 = tid * 4, b = m4 >> 7, c = m4 & 127;
                float4 v = *(const float4*)(wsf + OFF_HG + m4);
                *(float4*)(pool + P_HF + b * 132 + c) = v;
            }
            __syncthreads();
            {
                int p = tid >> 3, k = tid & 7;
                int kind = p >> 4, r = (p >> 3) & 1, b = p & 7;
                const float* wrow = pool + (kind ? P_WSKIP : P_WRES) + l * 256 + r * 128;
                float acc = 0.f;
                #pragma unroll
                for (int i = 0; i < 16; ++i) {
                    int jj = (i + 2 * k) & 15;
                    acc += wrow[k * 16 + jj] * pool[P_HF + b * 132 + k * 16 + jj];
                }
                acc += __shfl_xor(acc, 1); acc += __shfl_xor(acc, 2); acc += __shfl_xor(acc, 4);
                if (k == 0) {
                    if (!kind) {
                        if (l < 19) {
                            int rl = (l == 0) ? (P_RES0 + cur * 1056) : P_RESF;
                            float v = pool[rl + b * 132 + 2 * J + r] + acc + pool[P_RESB + l * 2 + r];
                            wsf[OFF_RESG + b * 128 + 2 * J + r] = v;
                            int d = c_dil[l + 1];
                            wsf[OFF_BUF + c_bufoff[l + 1] + ((size_t)(t & (d - 1)) << 10) +
                                b * 128 + 2 * J + r] = v;
                        }
                    } else {
                        pool[P_SKACC + r * 8 + b] += acc + pool[P_SKIPB + l * 2 + r];
                    }
                }
            }
            if (l == 19) {
                __syncthreads();
                if (tid < 16) {
                    int r = tid & 1, b = tid >> 1;
                    wsf[OFF_SKIPG + b * 128 + 2 * J + r] = pool[P_SKACC + r * 8 + b];
                }
            }
            gbar(flags, bid++);
        }

        // ---- head ----
        // H1: s = relu(skip) @ fc^T + sfc  (slice rows 2J..2J+1)
        {
            int m4 = tid * 4, b = m4 >> 7, c = m4 & 127;
            float4 v = *(const float4*)(wsf + OFF_SKIPG + m4);
            *(float4*)(pool + P_HF + b * 132 + c) = v;
        }
        __syncthreads();
        {
            int p = tid >> 4, k = tid & 15, r = p >> 3, b = p & 7;
            float acc = 0.f;
            #pragma unroll
            for (int i = 0; i < 8; ++i) {
                int jj = (i + k) & 7;
                acc += pool[P_WFC + r * 128 + k * 8 + jj] *
                       fmaxf(pool[P_HF + b * 132 + k * 8 + jj], 0.f);
            }
            acc += __shfl_xor(acc, 1); acc += __shfl_xor(acc, 2);
            acc += __shfl_xor(acc, 4); acc += __shfl_xor(acc, 8);
            if (k == 0) wsf[OFF_SG + b * 128 + 2 * J + r] = acc + pool[P_SFC + r * 8 + b];
        }
        gbar(flags, bid++);
        // H2: logits = relu(s) @ logits_w^T + logits_b (slice rows 4J..4J+3)
        {
            int m4 = tid * 4, b = m4 >> 7, c = m4 & 127;
            float4 v = *(const float4*)(wsf + OFF_SG + m4);
            v.x = fmaxf(v.x, 0.f); v.y = fmaxf(v.y, 0.f);
            v.z = fmaxf(v.z, 0.f); v.w = fmaxf(v.w, 0.f);
            *(float4*)(pool + P_HF + b * 132 + c) = v;
        }
        __syncthreads();
        {
            int w = tid >> 6, lane = tid & 63, b = lane >> 3, k = lane & 7;
            float acc = 0.f;
            #pragma unroll
            for (int i = 0; i < 16; ++i) {
                int jj = (i + 2 * k) & 15;
                acc += pool[P_WLOG + w * 128 + k * 16 + jj] * pool[P_HF + b * 132 + k * 16 + jj];
            }
            acc += __shfl_xor(acc, 1); acc += __shfl_xor(acc, 2); acc += __shfl_xor(acc, 4);
            if (k == 0) {
                float v = acc + pool[P_LOGB + w];
                wsf[OFF_LGG + b * 256 + 4 * J + w] = v;
                out[4096 + ((size_t)(t * BB + b)) * 256 + 4 * J + w] = v;
            }
        }
        gbar(flags, bid++);
        // H3: everyone reads full logits, per-batch argmax (replicated)
        for (int s = 0; s < 2; ++s) {
            int m4 = (tid + s * 256) * 4, b = m4 >> 8, q = m4 & 255;
            float4 v = *(const float4*)(wsf + OFF_LGG + m4);
            *(float4*)(pool + P_RING + b * 260 + q) = v;
        }
        __syncthreads();
        {
            int b = tid >> 5, j = tid & 31;
            float best = -3.4e38f; int bi = 0;
            for (int s = 0; s < 8; ++s) {
                int q = s * 32 + j;
                float v = pool[P_RING + b * 260 + q];
                if (v > best) { best = v; bi = q; }
            }
            for (int m = 16; m >= 1; m >>= 1) {
                float ov = __shfl_xor(best, m, 32);
                int   oi = __shfl_xor(bi, m, 32);
                if (ov > best || (ov == best && oi < bi)) { best = ov; bi = oi; }
            }
            if (j == 0) {
                pool[P_XNEW + b] = (float)bi;
                if (J == 0) out[t * BB + b] = (float)bi;
            }
        }
        __syncthreads();
        if (tid < 8) {
            pool[P_XPREV + tid] = pool[P_XCUR + tid];
            pool[P_XCUR + tid]  = pool[P_XNEW + tid] * (1.f / 255.f) - 0.5f;
        }
        __syncthreads();
    }
}

// ============================================================
extern "C" void kernel_launch(void* const* d_in, const int* in_sizes, int n_in,
                              void* d_out, int out_size, void* d_ws, size_t ws_size,
                              hipStream_t stream) {
    const float* enc      = (const float*)d_in[0];
    const float* first_w  = (const float*)d_in[1];
    const float* first_b  = (const float*)d_in[2];
    const float* causal_w = (const float*)d_in[3];
    const float* causal_b = (const float*)d_in[4];
    const float* cond_w   = (const float*)d_in[5];
    const float* cond_b   = (const float*)d_in[6];
    const float* res_w    = (const float*)d_in[7];
    const float* res_b    = (const float*)d_in[8];
    const float* skip_w   = (const float*)d_in[9];
    const float* skip_b   = (const float*)d_in[10];
    const float* skipc_w  = (const float*)d_in[11];
    const float* skipc_b  = (const float*)d_in[12];
    const float* fc_w     = (const float*)d_in[13];
    const float* fc_b     = (const float*)d_in[14];
    const float* condf_w  = (const float*)d_in[15];
    const float* condf_b  = (const float*)d_in[16];
    const float* logits_w = (const float*)d_in[17];
    const float* logits_b = (const float*)d_in[18];

    float* wsf = (float*)d_ws;
    float* out = (float*)d_out;
    int* flags = (int*)(wsf + OFF_FLAGS);

    wn_prep<<<(NFLAGS + 255) / 256, 256, 0, stream>>>(flags);
    wn_gen<<<NBLK, NTHR, POOL_FL * 4, stream>>>(
        enc, first_w, first_b, causal_w, causal_b, cond_w, cond_b,
        res_w, res_b, skip_w, skip_b, skipc_w, skipc_b, fc_w, fc_b,
        condf_w, condf_b, logits_w, logits_b, wsf, out);
}

// Round 5
// 52998.279 us; speedup vs baseline: 2.8561x; 1.7372x over previous
//
#include <hip/hip_runtime.h>
#include <math.h>

// ---------------- problem constants ----------------
#define BB 8
#define TT 512
#define LL 20
#define NBLK 64
#define NTHR 256

typedef float f4 __attribute__((ext_vector_type(4)));
typedef unsigned long long ull;

__constant__ int c_dil[LL] = {1,2,4,8,16,32,64,128,256,512,
                              1,2,4,8,16,32,64,128,256,512};
// float offset of each layer's dilation ring (slot stride 1024 = 8b*128)
__constant__ int c_roff[LL] = {-1,0,2048,6144,14336,30720,63488,129024,260096,522240,
                               1046528,1047552,1049600,1053696,1061888,1078272,
                               1111040,1176576,1307648,1569792};

// ---------------- workspace layout (floats) ----------------
constexpr size_t OFF_RING = 0;          // 2045 slots * 1024 floats
constexpr size_t OFF_X    = 2094080;    // exchange: 4 slots * 768 float4

// ---------------- LDS pool offsets (floats) ----------------
#define P_WC     0        // [20][4][256]: g-rows; [0:128]=W0(prev) [128:256]=W1(res)
#define P_WRES   20480    // [20][2][128]
#define P_WSKIP  25600    // [20][2][128]
#define P_WSKIPC 30720    // [2][128]
#define P_WFC    30976    // [2][128]
#define P_WLOG   31232    // [4][128]
#define P_WF0    31744    // [128]
#define P_WF1    31872    // [128]
#define P_FB     32000    // [128]
#define P_CONDZ  32128    // [20][4][8]
#define P_SFC    32768    // [2][8]
#define P_RESB   32784    // [20][2]
#define P_SKIPB  32824    // [20][2]
#define P_LOGB   32864    // [4]
#define P_SKIPCB 32868    // [2]
#define P_XCUR   32870    // [8]
#define P_XPREV  32878    // [8]
#define P_XNEW   32886    // [8] (+2 pad)
#define P_SZ     32896    // [32]
#define P_SL     32928    // [32]
#define P_SKACC  32960    // [16]
#define P_CF     32976    // [8][66]
#define P_PREVF  33504    // [8][132]   (head: logits gather [8][260] aliases PREVF+HF)
#define P_HF     34560    // [8][132]
#define P_RESF   35616    // [8][132]
#define P_RES0   36672    // [2][8][132]
#define POOL_FL  38784    // 155,136 bytes

// ---------------- coherent 16B exchange primitives (sc0 sc1 -> L3) ----------
__device__ __forceinline__ f4 ldx(const f4* p) {
    f4 r;
    asm volatile("global_load_dwordx4 %0, %1, off sc0 sc1\n\ts_waitcnt vmcnt(0)"
                 : "=v"(r) : "v"(p) : "memory");
    return r;
}
__device__ __forceinline__ void ldx2(const f4* p0, const f4* p1, f4& a, f4& b) {
    asm volatile("global_load_dwordx4 %0, %2, off sc0 sc1\n\t"
                 "global_load_dwordx4 %1, %3, off sc0 sc1\n\t"
                 "s_waitcnt vmcnt(0)"
                 : "=v"(a), "=v"(b) : "v"(p0), "v"(p1) : "memory");
}
__device__ __forceinline__ void stx(f4* p, f4 v) {
    asm volatile("s_waitcnt vmcnt(0)\n\t"
                 "global_store_dwordx4 %0, %1, off sc0 sc1"
                 :: "v"(p), "v"(v) : "memory");
}

// payload element E in [0,16): r=E>>3, b=E&7; vec layout [3 payload | tag]
__device__ __forceinline__ void publish16(f4* slot, int J, const float* sl, int e) {
    if (threadIdx.x < 6) {
        int q = threadIdx.x;
        f4 v;
        v.x = sl[3*q];
        v.y = (3*q+1 < 16) ? sl[3*q+1] : 0.f;
        v.z = (3*q+2 < 16) ? sl[3*q+2] : 0.f;
        v.w = __int_as_float(e);
        stx(slot + J*6 + q, v);
    }
}
__device__ __forceinline__ void scat16(float* dst, f4 v, int vi, bool dorelu) {
    int j = vi / 6, q = vi - 6*j;
    #pragma unroll
    for (int i = 0; i < 3; ++i) {
        int E = 3*q + i;
        if (E < 16) {
            float x = v[i];
            if (dorelu) x = fmaxf(x, 0.f);
            dst[(E & 7)*132 + 2*j + (E >> 3)] = x;
        }
    }
}
__device__ __forceinline__ void consume16(const f4* slot, int e, float* dst, bool dorelu) {
    int m = threadIdx.x;
    const f4 *p0 = slot + m, *p1 = slot + 256 + m;
    f4 a, b;
    bool two = (m < 128);
    if (two) ldx2(p0, p1, a, b); else a = ldx(p0);
    while (__float_as_int(a.w) != e) { __builtin_amdgcn_s_sleep(1); a = ldx(p0); }
    if (two) { while (__float_as_int(b.w) != e) { __builtin_amdgcn_s_sleep(1); b = ldx(p1); } }
    scat16(dst, a, m, dorelu);
    if (two) scat16(dst, b, m + 256, dorelu);
}
__device__ __forceinline__ void publish32(f4* slot, int J, const float* sl, int e) {
    if (threadIdx.x < 11) {
        int q = threadIdx.x;
        f4 v;
        v.x = sl[3*q];
        v.y = (3*q+1 < 32) ? sl[3*q+1] : 0.f;
        v.z = (3*q+2 < 32) ? sl[3*q+2] : 0.f;
        v.w = __int_as_float(e);
        stx(slot + J*11 + q, v);
    }
}
__device__ __forceinline__ void scat32(float* dst, f4 v, int vi) {
    int j = vi / 11, q = vi - 11*j;
    #pragma unroll
    for (int i = 0; i < 3; ++i) {
        int E = 3*q + i;
        if (E < 32) dst[(E & 7)*260 + 4*j + (E >> 3)] = v[i];
    }
}
__device__ __forceinline__ void consume32(const f4* slot, int e, float* dst) {
    int m = threadIdx.x;
    const f4 *p0 = slot + m, *p1 = slot + 256 + m, *p2 = slot + 512 + m;
    f4 a, b, c;
    ldx2(p0, p1, a, b);
    bool three = (m < 192);
    if (three) c = ldx(p2);
    while (__float_as_int(a.w) != e) { __builtin_amdgcn_s_sleep(1); a = ldx(p0); }
    while (__float_as_int(b.w) != e) { __builtin_amdgcn_s_sleep(1); b = ldx(p1); }
    if (three) { while (__float_as_int(c.w) != e) { __builtin_amdgcn_s_sleep(1); c = ldx(p2); } }
    scat32(dst, a, m);
    scat32(dst, b, m + 256);
    if (three) scat32(dst, c, m + 512);
}

// ============================================================
__global__ __launch_bounds__(NTHR, 1) void wn_gen(
    const float* __restrict__ enc,
    const float* __restrict__ first_w,  const float* __restrict__ first_b,
    const float* __restrict__ causal_w, const float* __restrict__ causal_b,
    const float* __restrict__ cond_w,   const float* __restrict__ cond_b,
    const float* __restrict__ res_w,    const float* __restrict__ res_b,
    const float* __restrict__ skip_w,   const float* __restrict__ skip_b,
    const float* __restrict__ skipc_w,  const float* __restrict__ skipc_b,
    const float* __restrict__ fc_w,     const float* __restrict__ fc_b,
    const float* __restrict__ condf_w,  const float* __restrict__ condf_b,
    const float* __restrict__ logits_w, const float* __restrict__ logits_b,
    float* __restrict__ wsf, float* __restrict__ out)
{
    extern __shared__ float pool[];
    const int tid = threadIdx.x;
    const int J = blockIdx.x;
    float* ring = wsf + OFF_RING;
    f4* xb = (f4*)(wsf + OFF_X);

    // ---------------- init: weight slices -> LDS ----------------
    for (int m = tid; m < 20480; m += NTHR) {
        int l = m >> 10, rem = m & 1023, g = rem >> 8, i = rem & 255;
        int grow = (g < 2) ? (2*J + g) : (128 + 2*J + (g - 2));
        int col = i & 127, k = i >> 7;   // k=0 -> W0(prev), k=1 -> W1(res)
        pool[P_WC + m] = causal_w[((size_t)(l*256 + grow)*128 + col)*2 + k];
    }
    for (int m = tid; m < 5120; m += NTHR) {
        int l = m >> 8, r = (m >> 7) & 1, i = m & 127;
        pool[P_WRES + m]  = res_w[(size_t)(l*128 + 2*J + r)*128 + i];
        pool[P_WSKIP + m] = skip_w[(size_t)(l*128 + 2*J + r)*128 + i];
    }
    if (tid < 256) {
        int r = tid >> 7, i = tid & 127;
        pool[P_WSKIPC + tid] = skipc_w[(size_t)(2*J + r)*128 + i];
        pool[P_WFC + tid]    = fc_w[(size_t)(2*J + r)*128 + i];
    }
    for (int m = tid; m < 512; m += NTHR) {
        int w = m >> 7, i = m & 127;
        pool[P_WLOG + m] = logits_w[(size_t)(4*J + w)*128 + i];
    }
    if (tid < 128) {
        pool[P_WF0 + tid] = first_w[2*tid];
        pool[P_WF1 + tid] = first_w[2*tid + 1];
        pool[P_FB + tid]  = first_b[tid];
    }
    if (tid < 40) {
        int l = tid >> 1, r = tid & 1;
        pool[P_RESB + tid]  = res_b[l*128 + 2*J + r];
        pool[P_SKIPB + tid] = skip_b[l*128 + 2*J + r];
    }
    if (tid < 4) pool[P_LOGB + tid] = logits_b[4*J + tid];
    if (tid < 2) pool[P_SKIPCB + tid] = skipc_b[2*J + tid];
    for (int m = tid; m < 2112; m += NTHR) pool[P_RES0 + m] = 0.f;
    if (tid < 8) { pool[P_XCUR + tid] = 128.f/255.f - 0.5f; pool[P_XPREV + tid] = 0.f; }
    __syncthreads();

    int e = 0;   // exchange epoch: ++ once per PUBLISH; deferred consume uses
                 // the counter value as-is (protocol bug in r4 was ++ on consume)

    for (int t = 0; t < TT; ++t) {
        // ---- per-chunk precompute (c changes every 64 steps) ----
        if ((t & 63) == 0) {
            int te = t >> 6;
            for (int m = tid; m < 512; m += NTHR) {
                int b = m >> 6, j = m & 63;
                pool[P_CF + b*66 + j] = enc[(size_t)b*512 + j*8 + te];
            }
            __syncthreads();
            for (int m = tid; m < 640; m += NTHR) {
                int l = m >> 5, rem = m & 31, g = rem >> 3, b = rem & 7;
                int grow = (g < 2) ? (2*J + g) : (128 + 2*J + (g - 2));
                float acc = causal_b[l*256 + grow] + cond_b[l*256 + grow];
                const float* cw = cond_w + (size_t)(l*256 + grow)*64;
                const float* cf = pool + P_CF + b*66;
                for (int j = 0; j < 64; ++j) acc += cw[j]*cf[j];
                pool[P_CONDZ + l*32 + g*8 + b] = acc;
            }
            if (tid < 16) {
                int r = tid >> 3, b = tid & 7, row = 2*J + r;
                float acc = fc_b[row] + condf_b[row];
                const float* cw = condf_w + (size_t)row*64;
                const float* cf = pool + P_CF + b*66;
                for (int j = 0; j < 64; ++j) acc += cw[j]*cf[j];
                pool[P_SFC + r*8 + b] = acc;
            }
            __syncthreads();
        }

        const int cur = t & 1;
        // ---- res_0 (full, local) ----
        for (int m = tid; m < 1024; m += NTHR) {
            int b = m >> 7, r = m & 127;
            pool[P_RES0 + cur*1056 + b*132 + r] =
                pool[P_XPREV + b]*pool[P_WF0 + r] + pool[P_XCUR + b]*pool[P_WF1 + r] + pool[P_FB + r];
        }
        __syncthreads();
        // ---- skip init slice -> P_SKACC ----
        {
            int w = tid >> 6, lane = tid & 63, b = lane >> 3, k = lane & 7;
            if (w < 2) {
                const float* wr = pool + P_WSKIPC + w*128;
                const float* rs = pool + P_RES0 + cur*1056 + b*132;
                float acc = 0.f;
                #pragma unroll
                for (int i = 0; i < 16; ++i) { int j = k + 8*i; acc += wr[j]*rs[j]; }
                acc += __shfl_xor(acc,1); acc += __shfl_xor(acc,2); acc += __shfl_xor(acc,4);
                if (k == 0) pool[P_SKACC + w*8 + b] = acc + pool[P_SKIPCB + w];
            }
        }

        // ---- layer loop ----
        for (int l = 0; l < LL; ++l) {
            const float* resP  = (l == 0) ? pool + P_RES0 + cur*1056      : pool + P_RESF;
            const float* prevP = (l == 0) ? pool + P_RES0 + (cur^1)*1056  : pool + P_PREVF;

            // (1) consume res_l (published at end of prev layer, epoch = current e)
            if (l >= 1) consume16(xb + (size_t)(e & 3)*768, e, pool + P_RESF, false);

            // (2) issue prev_{l+1} ring prefetch
            ull pfa = 0, pfb = 0;
            if (l <= 18) {
                int d = c_dil[l+1];
                if (t >= d) {
                    const float* rp = ring + c_roff[l+1] + (size_t)(t & (d-1))*1024 + tid*4;
                    pfa = __hip_atomic_load((const ull*)rp,     __ATOMIC_RELAXED, __HIP_MEMORY_SCOPE_AGENT);
                    pfb = __hip_atomic_load((const ull*)(rp+2), __ATOMIC_RELAXED, __HIP_MEMORY_SCOPE_AGENT);
                }
            }
            __syncthreads();

            // (4) z slice: 4 waves <-> 4 z-rows; lane (b,k): j = k+8i (bank-clean)
            {
                int g = tid >> 6, lane = tid & 63, b = lane >> 3, k = lane & 7;
                const float* wrow = pool + P_WC + (l*4 + g)*256;
                const float* pv = prevP + b*132;
                const float* rs = resP + b*132;
                float acc = 0.f;
                #pragma unroll
                for (int i = 0; i < 16; ++i) {
                    int j = k + 8*i;
                    acc += wrow[j]*pv[j] + wrow[128 + j]*rs[j];
                }
                acc += __shfl_xor(acc,1); acc += __shfl_xor(acc,2); acc += __shfl_xor(acc,4);
                if (k == 0) pool[P_SZ + g*8 + b] = acc;
            }
            __syncthreads();
            // (5) h slice
            if (tid < 16) {
                int r = tid & 1, b = tid >> 1;
                float g = pool[P_SZ + r*8 + b]       + pool[P_CONDZ + l*32 + r*8 + b];
                float o = pool[P_SZ + (2+r)*8 + b]   + pool[P_CONDZ + l*32 + (2+r)*8 + b];
                pool[P_SL + r*8 + b] = (1.f/(1.f + expf(-g))) * tanhf(o);
            }
            __syncthreads();
            // (6)(7) exchange h_l
            ++e;
            publish16(xb + (size_t)(e & 3)*768, J, pool + P_SL, e);
            consume16(xb + (size_t)(e & 3)*768, e, pool + P_HF, false);
            __syncthreads();
            // (8) res_{l+1} slice (waves 0,1) + skip accum (waves 2,3)
            {
                int w = tid >> 6, lane = tid & 63, b = lane >> 3, k = lane & 7;
                int r = w & 1, isSkip = w >> 1;
                if (isSkip || l <= 18) {
                    const float* wr = pool + (isSkip ? P_WSKIP : P_WRES) + (l*2 + r)*128;
                    const float* hh = pool + P_HF + b*132;
                    float acc = 0.f;
                    #pragma unroll
                    for (int i = 0; i < 16; ++i) { int j = k + 8*i; acc += wr[j]*hh[j]; }
                    acc += __shfl_xor(acc,1); acc += __shfl_xor(acc,2); acc += __shfl_xor(acc,4);
                    if (k == 0) {
                        if (isSkip) {
                            pool[P_SKACC + r*8 + b] += acc + pool[P_SKIPB + l*2 + r];
                        } else {
                            float v = resP[b*132 + 2*J + r] + acc + pool[P_RESB + l*2 + r];
                            pool[P_SL + r*8 + b] = v;
                            int d = c_dil[l+1];
                            float* wp = ring + c_roff[l+1] + (size_t)(t & (d-1))*1024 + b*128 + 2*J + r;
                            __hip_atomic_store(wp, v, __ATOMIC_RELAXED, __HIP_MEMORY_SCOPE_AGENT);
                        }
                    }
                }
            }
            // (9) land prefetched prev_{l+1} into prevF
            if (l <= 18) {
                int b = tid >> 5, c = (tid & 31)*4;
                union { ull u; float f[2]; } u0, u1;
                u0.u = pfa; u1.u = pfb;
                float* dp = pool + P_PREVF + b*132 + c;
                dp[0] = u0.f[0]; dp[1] = u0.f[1]; dp[2] = u1.f[0]; dp[3] = u1.f[1];
            }
            __syncthreads();
            // (10) publish res_{l+1} (consumed at next layer's step (1), same epoch)
            if (l <= 18) { ++e; publish16(xb + (size_t)(e & 3)*768, J, pool + P_SL, e); }
        }

        // ---- head ----
        // C: skip slices
        ++e;
        publish16(xb + (size_t)(e & 3)*768, J, pool + P_SKACC, e);
        consume16(xb + (size_t)(e & 3)*768, e, pool + P_HF, false);
        __syncthreads();
        // s slice: waves 0,1 over relu(skip)
        {
            int w = tid >> 6, lane = tid & 63, b = lane >> 3, k = lane & 7;
            if (w < 2) {
                const float* wr = pool + P_WFC + w*128;
                const float* sk = pool + P_HF + b*132;
                float acc = 0.f;
                #pragma unroll
                for (int i = 0; i < 16; ++i) { int j = k + 8*i; acc += wr[j]*fmaxf(sk[j], 0.f); }
                acc += __shfl_xor(acc,1); acc += __shfl_xor(acc,2); acc += __shfl_xor(acc,4);
                if (k == 0) pool[P_SL + w*8 + b] = acc + pool[P_SFC + w*8 + b];
            }
        }
        __syncthreads();
        // D: s slices (consumers apply relu on scatter)
        ++e;
        publish16(xb + (size_t)(e & 3)*768, J, pool + P_SL, e);
        consume16(xb + (size_t)(e & 3)*768, e, pool + P_RESF, true);
        __syncthreads();
        // logits slice: 4 waves <-> rows 4J..4J+3
        {
            int g = tid >> 6, lane = tid & 63, b = lane >> 3, k = lane & 7;
            const float* wr = pool + P_WLOG + g*128;
            const float* sv = pool + P_RESF + b*132;
            float acc = 0.f;
            #pragma unroll
            for (int i = 0; i < 16; ++i) { int j = k + 8*i; acc += wr[j]*sv[j]; }
            acc += __shfl_xor(acc,1); acc += __shfl_xor(acc,2); acc += __shfl_xor(acc,4);
            if (k == 0) {
                float v = acc + pool[P_LOGB + g];
                pool[P_SZ + g*8 + b] = v;
                out[4096 + ((size_t)(t*BB + b))*256 + 4*J + g] = v;
            }
        }
        __syncthreads();
        // E: logits (32 floats/block); gather into lgF (stride 260, aliases PREVF+HF)
        ++e;
        publish32(xb + (size_t)(e & 3)*768, J, pool + P_SZ, e);
        consume32(xb + (size_t)(e & 3)*768, e, pool + P_PREVF);
        __syncthreads();
        // argmax (replicated in every block; first-index tie-break)
        {
            int b = tid >> 5, j = tid & 31;
            float best = -3.4e38f; int bi = 0;
            for (int s = 0; s < 8; ++s) {
                int q = s*32 + j;
                float v = pool[P_PREVF + b*260 + q];
                if (v > best) { best = v; bi = q; }
            }
            for (int m = 16; m >= 1; m >>= 1) {
                float ov = __shfl_xor(best, m, 32);
                int   oi = __shfl_xor(bi, m, 32);
                if (ov > best || (ov == best && oi < bi)) { best = ov; bi = oi; }
            }
            if (j == 0) {
                pool[P_XNEW + b] = (float)bi;
                if (J == 0) out[t*BB + b] = (float)bi;
            }
        }
        __syncthreads();
        if (tid < 8) {
            pool[P_XPREV + tid] = pool[P_XCUR + tid];
            pool[P_XCUR + tid]  = pool[P_XNEW + tid]*(1.f/255.f) - 0.5f;
        }
        __syncthreads();
    }
}

// ============================================================
extern "C" void kernel_launch(void* const* d_in, const int* in_sizes, int n_in,
                              void* d_out, int out_size, void* d_ws, size_t ws_size,
                              hipStream_t stream) {
    const float* enc      = (const float*)d_in[0];
    const float* first_w  = (const float*)d_in[1];
    const float* first_b  = (const float*)d_in[2];
    const float* causal_w = (const float*)d_in[3];
    const float* causal_b = (const float*)d_in[4];
    const float* cond_w   = (const float*)d_in[5];
    const float* cond_b   = (const float*)d_in[6];
    const float* res_w    = (const float*)d_in[7];
    const float* res_b    = (const float*)d_in[8];
    const float* skip_w   = (const float*)d_in[9];
    const float* skip_b   = (const float*)d_in[10];
    const float* skipc_w  = (const float*)d_in[11];
    const float* skipc_b  = (const float*)d_in[12];
    const float* fc_w     = (const float*)d_in[13];
    const float* fc_b     = (const float*)d_in[14];
    const float* condf_w  = (const float*)d_in[15];
    const float* condf_b  = (const float*)d_in[16];
    const float* logits_w = (const float*)d_in[17];
    const float* logits_b = (const float*)d_in[18];

    float* wsf = (float*)d_ws;
    float* out = (float*)d_out;

    wn_gen<<<NBLK, NTHR, POOL_FL*4, stream>>>(
        enc, first_w, first_b, causal_w, causal_b, cond_w, cond_b,
        res_w, res_b, skip_w, skip_b, skipc_w, skipc_b, fc_w, fc_b,
        condf_w, condf_b, logits_w, logits_b, wsf, out);
}

// Round 6
// 37495.660 us; speedup vs baseline: 4.0370x; 1.4135x over previous
//
#include <hip/hip_runtime.h>
#include <math.h>

// ---------------- problem constants ----------------
#define BB 8
#define TT 512
#define LL 20
#define NBLK 64
#define NTHR 256

typedef float f4 __attribute__((ext_vector_type(4)));
typedef unsigned long long ull;

__constant__ int c_dil[LL] = {1,2,4,8,16,32,64,128,256,512,
                              1,2,4,8,16,32,64,128,256,512};
// double-buffered rings: layer lam has 2*d slots of 1024 floats
__constant__ int c_roff[LL] = {-1,0,4096,12288,28672,61440,126976,258048,520192,1044480,
                               2093056,2095104,2099200,2107392,2123776,2156544,
                               2222080,2353152,2615296,3139584};

// ---------------- workspace layout (floats) ----------------
constexpr size_t OFF_RING = 0;          // 4,188,160 floats
constexpr size_t OFF_X    = 4188160;    // exchange: 4 slots * 768 float4

// ---------------- LDS pool offsets (floats) ----------------
#define P_WC     0        // [20][4][256]: z-row g: [0:128]=W0(prev) [128:256]=W1(res)
#define P_F      20480    // [19][4][128]: F_l = W1_{l+1}slice · Wres_l^T
#define P_WST    30208    // [512]: per-layer staged res/skip rows (res 0..255, skip 256..511)
#define P_WSKIPC 30720    // [2][128]
#define P_WFC    30976    // [2][128]
#define P_WLOG   31232    // [4][128]
#define P_WF0    31744    // [128]
#define P_WF1    31872    // [128]
#define P_FB     32000    // [128]
#define P_CONDZ  32128    // [20][4][8]  (includes zb fold)
#define P_SFC    32768    // [2][8]
#define P_RESB   32784    // [20][2]
#define P_SKIPB  32824    // [20][2]
#define P_ZB     32864    // [20][4]: W1_l · res_b[l-1]  (l=0 -> 0)
#define P_LOGB   32944    // [4]
#define P_SKIPCB 32948    // [2]
#define P_XCUR   32950    // [8]
#define P_XPREV  32958    // [8]
#define P_XNEW   32966    // [8] (+2 pad)
#define P_SZ     32976    // [32]
#define P_SL     33008    // [32]
#define P_SKACC  33040    // [16]
#define P_R2     33056    // [16]: block's own res rows (running)
#define P_CF     33072    // [8][66]
#define P_PREVF  33600    // [8][132]   (head: logits gather [8][260] spans PREVF+HF)
#define P_HF     34656    // [8][132]
#define P_RESF   35712    // [8][132]
#define P_RES0   36768    // [2][8][132]
#define POOL_FL  38880    // 155,520 bytes

// ---------------- coherent 16B exchange primitives (sc0 sc1 -> L3) ----------
__device__ __forceinline__ f4 ldx(const f4* p) {
    f4 r;
    asm volatile("global_load_dwordx4 %0, %1, off sc0 sc1\n\ts_waitcnt vmcnt(0)"
                 : "=v"(r) : "v"(p) : "memory");
    return r;
}
__device__ __forceinline__ void ldx2(const f4* p0, const f4* p1, f4& a, f4& b) {
    asm volatile("global_load_dwordx4 %0, %2, off sc0 sc1\n\t"
                 "global_load_dwordx4 %1, %3, off sc0 sc1\n\t"
                 "s_waitcnt vmcnt(0)"
                 : "=v"(a), "=v"(b) : "v"(p0), "v"(p1) : "memory");
}
__device__ __forceinline__ void stx(f4* p, f4 v) {
    asm volatile("s_waitcnt vmcnt(0)\n\t"
                 "global_store_dwordx4 %0, %1, off sc0 sc1"
                 :: "v"(p), "v"(v) : "memory");
}

// payload element E in [0,16): r=E>>3, b=E&7; vec layout [3 payload | tag]
__device__ __forceinline__ void publish16(f4* slot, int J, const float* sl, int e) {
    if (threadIdx.x < 6) {
        int q = threadIdx.x;
        f4 v;
        v.x = sl[3*q];
        v.y = (3*q+1 < 16) ? sl[3*q+1] : 0.f;
        v.z = (3*q+2 < 16) ? sl[3*q+2] : 0.f;
        v.w = __int_as_float(e);
        stx(slot + J*6 + q, v);
    }
}
__device__ __forceinline__ void scat16(float* dst, f4 v, int vi, bool dorelu) {
    int j = vi / 6, q = vi - 6*j;
    #pragma unroll
    for (int i = 0; i < 3; ++i) {
        int E = 3*q + i;
        if (E < 16) {
            float x = v[i];
            if (dorelu) x = fmaxf(x, 0.f);
            dst[(E & 7)*132 + 2*j + (E >> 3)] = x;
        }
    }
}
__device__ __forceinline__ void consume16(const f4* slot, int e, float* dst, bool dorelu) {
    int m = threadIdx.x;
    const f4 *p0 = slot + m, *p1 = slot + 256 + m;
    f4 a, b;
    bool two = (m < 128);
    if (two) ldx2(p0, p1, a, b); else a = ldx(p0);
    while (__float_as_int(a.w) != e) { __builtin_amdgcn_s_sleep(1); a = ldx(p0); }
    if (two) { while (__float_as_int(b.w) != e) { __builtin_amdgcn_s_sleep(1); b = ldx(p1); } }
    scat16(dst, a, m, dorelu);
    if (two) scat16(dst, b, m + 256, dorelu);
}
__device__ __forceinline__ void publish32(f4* slot, int J, const float* sl, int e) {
    if (threadIdx.x < 11) {
        int q = threadIdx.x;
        f4 v;
        v.x = sl[3*q];
        v.y = (3*q+1 < 32) ? sl[3*q+1] : 0.f;
        v.z = (3*q+2 < 32) ? sl[3*q+2] : 0.f;
        v.w = __int_as_float(e);
        stx(slot + J*11 + q, v);
    }
}
__device__ __forceinline__ void scat32(float* dst, f4 v, int vi) {
    int j = vi / 11, q = vi - 11*j;
    #pragma unroll
    for (int i = 0; i < 3; ++i) {
        int E = 3*q + i;
        if (E < 32) dst[(E & 7)*260 + 4*j + (E >> 3)] = v[i];
    }
}
__device__ __forceinline__ void consume32(const f4* slot, int e, float* dst) {
    int m = threadIdx.x;
    const f4 *p0 = slot + m, *p1 = slot + 256 + m, *p2 = slot + 512 + m;
    f4 a, b, c;
    ldx2(p0, p1, a, b);
    bool three = (m < 192);
    if (three) c = ldx(p2);
    while (__float_as_int(a.w) != e) { __builtin_amdgcn_s_sleep(1); a = ldx(p0); }
    while (__float_as_int(b.w) != e) { __builtin_amdgcn_s_sleep(1); b = ldx(p1); }
    if (three) { while (__float_as_int(c.w) != e) { __builtin_amdgcn_s_sleep(1); c = ldx(p2); } }
    scat32(dst, a, m);
    scat32(dst, b, m + 256);
    if (three) scat32(dst, c, m + 512);
}

// ============================================================
__global__ __launch_bounds__(NTHR, 1) void wn_gen(
    const float* __restrict__ enc,
    const float* __restrict__ first_w,  const float* __restrict__ first_b,
    const float* __restrict__ causal_w, const float* __restrict__ causal_b,
    const float* __restrict__ cond_w,   const float* __restrict__ cond_b,
    const float* __restrict__ res_w,    const float* __restrict__ res_b,
    const float* __restrict__ skip_w,   const float* __restrict__ skip_b,
    const float* __restrict__ skipc_w,  const float* __restrict__ skipc_b,
    const float* __restrict__ fc_w,     const float* __restrict__ fc_b,
    const float* __restrict__ condf_w,  const float* __restrict__ condf_b,
    const float* __restrict__ logits_w, const float* __restrict__ logits_b,
    float* __restrict__ wsf, float* __restrict__ out)
{
    extern __shared__ float pool[];
    const int tid = threadIdx.x;
    const int J = blockIdx.x;
    float* ring = wsf + OFF_RING;
    f4* xb = (f4*)(wsf + OFF_X);

    // ---------------- init: weight slices -> LDS ----------------
    for (int m = tid; m < 20480; m += NTHR) {
        int l = m >> 10, rem = m & 1023, g = rem >> 8, i = rem & 255;
        int grow = (g < 2) ? (2*J + g) : (128 + 2*J + (g - 2));
        int col = i & 127, k = i >> 7;   // k=0 -> W0(prev), k=1 -> W1(res)
        pool[P_WC + m] = causal_w[((size_t)(l*256 + grow)*128 + col)*2 + k];
    }
    if (tid < 256) {
        int r = tid >> 7, i = tid & 127;
        pool[P_WSKIPC + tid] = skipc_w[(size_t)(2*J + r)*128 + i];
        pool[P_WFC + tid]    = fc_w[(size_t)(2*J + r)*128 + i];
    }
    for (int m = tid; m < 512; m += NTHR) {
        int w = m >> 7, i = m & 127;
        pool[P_WLOG + m] = logits_w[(size_t)(4*J + w)*128 + i];
    }
    if (tid < 128) {
        pool[P_WF0 + tid] = first_w[2*tid];
        pool[P_WF1 + tid] = first_w[2*tid + 1];
        pool[P_FB + tid]  = first_b[tid];
    }
    if (tid < 40) {
        int l = tid >> 1, r = tid & 1;
        pool[P_RESB + tid]  = res_b[l*128 + 2*J + r];
        pool[P_SKIPB + tid] = skip_b[l*128 + 2*J + r];
    }
    if (tid < 4) pool[P_LOGB + tid] = logits_b[4*J + tid];
    if (tid < 2) pool[P_SKIPCB + tid] = skipc_b[2*J + tid];
    for (int m = tid; m < 2112; m += NTHR) pool[P_RES0 + m] = 0.f;
    if (tid < 8) { pool[P_XCUR + tid] = 128.f/255.f - 0.5f; pool[P_XPREV + tid] = 0.f; }
    __syncthreads();   // P_WC ready for F/zb compute

    // F_l[g][j] = sum_i W1_{l+1}[g][i] * res_w[l][i][j]   (l = 0..18)
    for (int l = 0; l < 19; ++l) {
        for (int m = tid; m < 512; m += NTHR) {
            int g = m >> 7, j = m & 127;
            const float* w1 = pool + P_WC + ((l+1)*4 + g)*256 + 128;
            const float* rw = res_w + (size_t)l*128*128 + j;
            float acc = 0.f;
            #pragma unroll 8
            for (int i = 0; i < 128; ++i) acc += w1[i] * rw[(size_t)i*128];
            pool[P_F + (l*4 + g)*128 + j] = acc;
        }
    }
    // zb_l[g] = W1_l[g] . res_b[l-1]  (l >= 1)
    if (tid < 80) {
        int l = tid >> 2, g = tid & 3;
        float acc = 0.f;
        if (l >= 1) {
            const float* w1 = pool + P_WC + (l*4 + g)*256 + 128;
            for (int i = 0; i < 128; ++i) acc += w1[i] * res_b[(l-1)*128 + i];
        }
        pool[P_ZB + tid] = acc;
    }
    __syncthreads();

    int e = 0;           // exchange epoch: ++ once per PUBLISH (uniform order)
    int er_pending = 0;  // epoch of most recent res publish

    for (int t = 0; t < TT; ++t) {
        // ---- per-chunk precompute ----
        if ((t & 63) == 0) {
            int te = t >> 6;
            for (int m = tid; m < 512; m += NTHR) {
                int b = m >> 6, j = m & 63;
                pool[P_CF + b*66 + j] = enc[(size_t)b*512 + j*8 + te];
            }
            __syncthreads();
            for (int m = tid; m < 640; m += NTHR) {
                int l = m >> 5, rem = m & 31, g = rem >> 3, b = rem & 7;
                int grow = (g < 2) ? (2*J + g) : (128 + 2*J + (g - 2));
                float acc = causal_b[l*256 + grow] + cond_b[l*256 + grow]
                          + pool[P_ZB + l*4 + g];
                const float* cw = cond_w + (size_t)(l*256 + grow)*64;
                const float* cf = pool + P_CF + b*66;
                for (int j = 0; j < 64; ++j) acc += cw[j]*cf[j];
                pool[P_CONDZ + l*32 + g*8 + b] = acc;
            }
            if (tid < 16) {
                int r = tid >> 3, b = tid & 7, row = 2*J + r;
                float acc = fc_b[row] + condf_b[row];
                const float* cw = condf_w + (size_t)row*64;
                const float* cf = pool + P_CF + b*66;
                for (int j = 0; j < 64; ++j) acc += cw[j]*cf[j];
                pool[P_SFC + r*8 + b] = acc;
            }
            __syncthreads();
        }

        const int cur = t & 1;
        // ---- res_0 (full, local) ----
        for (int m = tid; m < 1024; m += NTHR) {
            int b = m >> 7, r = m & 127;
            pool[P_RES0 + cur*1056 + b*132 + r] =
                pool[P_XPREV + b]*pool[P_WF0 + r] + pool[P_XCUR + b]*pool[P_WF1 + r] + pool[P_FB + r];
        }
        __syncthreads();
        // ---- skip init slice + r2 init ----
        {
            int w = tid >> 6, lane = tid & 63, b = lane >> 3, k = lane & 7;
            if (w < 2) {
                const float* wr = pool + P_WSKIPC + w*128;
                const float* rs = pool + P_RES0 + cur*1056 + b*132;
                float acc = 0.f;
                #pragma unroll
                for (int i = 0; i < 16; ++i) { int j = k + 8*i; acc += wr[j]*rs[j]; }
                acc += __shfl_xor(acc,1); acc += __shfl_xor(acc,2); acc += __shfl_xor(acc,4);
                if (k == 0) pool[P_SKACC + w*8 + b] = acc + pool[P_SKIPCB + w];
            }
        }
        if (tid < 16) {
            int r = tid >> 3, b = tid & 7;
            pool[P_R2 + r*8 + b] = pool[P_RES0 + cur*1056 + b*132 + 2*J + r];
        }

        // ---- layer loop: ONE blocking exchange (h) per layer ----
        for (int l = 0; l < LL; ++l) {
            // S1: z_l = W0.prev + W1.res_{l-1} + F_{l-1}.h_{l-1} + condz
            {
                int g = tid >> 6, lane = tid & 63, b = lane >> 3, k = lane & 7;
                const float* w0 = pool + P_WC + (l*4 + g)*256;
                const float* pv = ((l == 0) ? pool + P_RES0 + (cur^1)*1056 : pool + P_PREVF) + b*132;
                const float* rs = ((l <= 1) ? pool + P_RES0 + cur*1056 : pool + P_RESF) + b*132;
                float acc = 0.f;
                #pragma unroll
                for (int i = 0; i < 16; ++i) {
                    int j = k + 8*i;
                    acc += w0[j]*pv[j] + w0[128 + j]*rs[j];
                }
                if (l >= 1) {
                    const float* fm = pool + P_F + ((l-1)*4 + g)*128;
                    const float* hh = pool + P_HF + b*132;
                    #pragma unroll
                    for (int i = 0; i < 16; ++i) { int j = k + 8*i; acc += fm[j]*hh[j]; }
                }
                acc += __shfl_xor(acc,1); acc += __shfl_xor(acc,2); acc += __shfl_xor(acc,4);
                if (k == 0) pool[P_SZ + g*8 + b] = acc;
            }
            __syncthreads();
            // S3: h slice
            if (tid < 16) {
                int r = tid & 1, b = tid >> 1;
                float g = pool[P_SZ + r*8 + b]     + pool[P_CONDZ + l*32 + r*8 + b];
                float o = pool[P_SZ + (2+r)*8 + b] + pool[P_CONDZ + l*32 + (2+r)*8 + b];
                pool[P_SL + r*8 + b] = (1.f/(1.f + expf(-g))) * tanhf(o);
            }
            __syncthreads();
            // S5: publish h_l
            ++e; int eh = e;
            publish16(xb + (size_t)(eh & 3)*768, J, pool + P_SL, eh);
            // S6: stage this layer's res/skip weight rows (global, L2-resident)
            float wv0, wv1;
            {
                int r0 = tid >> 7, i0 = tid & 127;
                wv0 = res_w [(size_t)(l*128 + 2*J + r0)*128 + i0];
                wv1 = skip_w[(size_t)(l*128 + 2*J + r0)*128 + i0];
            }
            // S7: ring prefetch prev_{l+1} (double-buffered slots: race-free)
            ull pfa = 0, pfb = 0;
            if (l <= 18) {
                int d = c_dil[l+1];
                if (t >= d) {
                    int slot = (t - d) & (2*d - 1);
                    const float* rp = ring + c_roff[l+1] + (size_t)slot*1024 + tid*4;
                    pfa = __hip_atomic_load((const ull*)rp,     __ATOMIC_RELAXED, __HIP_MEMORY_SCOPE_AGENT);
                    pfb = __hip_atomic_load((const ull*)(rp+2), __ATOMIC_RELAXED, __HIP_MEMORY_SCOPE_AGENT);
                }
            }
            // S7.5: consume res_l (published a full layer ago -> latency hidden)
            if (l >= 1 && l <= 18)
                consume16(xb + (size_t)(er_pending & 3)*768, er_pending, pool + P_RESF, false);
            // S8: consume h_l (the one real RTT)
            consume16(xb + (size_t)(eh & 3)*768, eh, pool + P_HF, false);
            // S8.5: land staged weight rows
            pool[P_WST + tid] = wv0;
            pool[P_WST + 256 + tid] = wv1;
            __syncthreads();
            // S10: dres slice (waves 0,1) + skip accum (waves 2,3)
            {
                int w = tid >> 6, lane = tid & 63, b = lane >> 3, k = lane & 7;
                int r = w & 1, isSkip = w >> 1;
                if (isSkip || l <= 18) {
                    const float* wr = pool + P_WST + (isSkip ? 256 : 0) + r*128;
                    const float* hh = pool + P_HF + b*132;
                    float acc = 0.f;
                    #pragma unroll
                    for (int i = 0; i < 16; ++i) { int j = k + 8*i; acc += wr[j]*hh[j]; }
                    acc += __shfl_xor(acc,1); acc += __shfl_xor(acc,2); acc += __shfl_xor(acc,4);
                    if (k == 0) {
                        if (isSkip) {
                            pool[P_SKACC + r*8 + b] += acc + pool[P_SKIPB + l*2 + r];
                        } else {
                            float v = pool[P_R2 + r*8 + b] + acc + pool[P_RESB + l*2 + r];
                            pool[P_R2 + r*8 + b] = v;
                            pool[P_SL + r*8 + b] = v;
                            int d = c_dil[l+1];
                            int slot = t & (2*d - 1);
                            float* wp = ring + c_roff[l+1] + (size_t)slot*1024 + b*128 + 2*J + r;
                            __hip_atomic_store(wp, v, __ATOMIC_RELAXED, __HIP_MEMORY_SCOPE_AGENT);
                        }
                    }
                }
            }
            __syncthreads();
            // S10b: publish res_{l+1} (consumed at layer l+1 S7.5)
            if (l <= 17) {
                ++e;
                publish16(xb + (size_t)(e & 3)*768, J, pool + P_SL, e);
                er_pending = e;
            }
            // S11: land prev prefetch
            if (l <= 18) {
                int b = tid >> 5, c = (tid & 31)*4;
                union { ull u; float f[2]; } u0, u1;
                u0.u = pfa; u1.u = pfb;
                float* dp = pool + P_PREVF + b*132 + c;
                dp[0] = u0.f[0]; dp[1] = u0.f[1]; dp[2] = u1.f[0]; dp[3] = u1.f[1];
            }
            __syncthreads();
        }

        // ---- head ----
        ++e;
        publish16(xb + (size_t)(e & 3)*768, J, pool + P_SKACC, e);
        consume16(xb + (size_t)(e & 3)*768, e, pool + P_HF, false);
        __syncthreads();
        {
            int w = tid >> 6, lane = tid & 63, b = lane >> 3, k = lane & 7;
            if (w < 2) {
                const float* wr = pool + P_WFC + w*128;
                const float* sk = pool + P_HF + b*132;
                float acc = 0.f;
                #pragma unroll
                for (int i = 0; i < 16; ++i) { int j = k + 8*i; acc += wr[j]*fmaxf(sk[j], 0.f); }
                acc += __shfl_xor(acc,1); acc += __shfl_xor(acc,2); acc += __shfl_xor(acc,4);
                if (k == 0) pool[P_SL + w*8 + b] = acc + pool[P_SFC + w*8 + b];
            }
        }
        __syncthreads();
        ++e;
        publish16(xb + (size_t)(e & 3)*768, J, pool + P_SL, e);
        consume16(xb + (size_t)(e & 3)*768, e, pool + P_RESF, true);   // relu on scatter
        __syncthreads();
        {
            int g = tid >> 6, lane = tid & 63, b = lane >> 3, k = lane & 7;
            const float* wr = pool + P_WLOG + g*128;
            const float* sv = pool + P_RESF + b*132;
            float acc = 0.f;
            #pragma unroll
            for (int i = 0; i < 16; ++i) { int j = k + 8*i; acc += wr[j]*sv[j]; }
            acc += __shfl_xor(acc,1); acc += __shfl_xor(acc,2); acc += __shfl_xor(acc,4);
            if (k == 0) {
                float v = acc + pool[P_LOGB + g];
                pool[P_SZ + g*8 + b] = v;
                out[4096 + ((size_t)(t*BB + b))*256 + 4*J + g] = v;
            }
        }
        __syncthreads();
        ++e;
        publish32(xb + (size_t)(e & 3)*768, J, pool + P_SZ, e);
        consume32(xb + (size_t)(e & 3)*768, e, pool + P_PREVF);   // [8][260] gather
        __syncthreads();
        // argmax (replicated; first-index tie-break)
        {
            int b = tid >> 5, j = tid & 31;
            float best = -3.4e38f; int bi = 0;
            for (int s = 0; s < 8; ++s) {
                int q = s*32 + j;
                float v = pool[P_PREVF + b*260 + q];
                if (v > best) { best = v; bi = q; }
            }
            for (int m = 16; m >= 1; m >>= 1) {
                float ov = __shfl_xor(best, m, 32);
                int   oi = __shfl_xor(bi, m, 32);
                if (ov > best || (ov == best && oi < bi)) { best = ov; bi = oi; }
            }
            if (j == 0) {
                pool[P_XNEW + b] = (float)bi;
                if (J == 0) out[t*BB + b] = (float)bi;
            }
        }
        __syncthreads();
        if (tid < 8) {
            pool[P_XPREV + tid] = pool[P_XCUR + tid];
            pool[P_XCUR + tid]  = pool[P_XNEW + tid]*(1.f/255.f) - 0.5f;
        }
        __syncthreads();
    }
}

// ============================================================
extern "C" void kernel_launch(void* const* d_in, const int* in_sizes, int n_in,
                              void* d_out, int out_size, void* d_ws, size_t ws_size,
                              hipStream_t stream) {
    const float* enc      = (const float*)d_in[0];
    const float* first_w  = (const float*)d_in[1];
    const float* first_b  = (const float*)d_in[2];
    const float* causal_w = (const float*)d_in[3];
    const float* causal_b = (const float*)d_in[4];
    const float* cond_w   = (const float*)d_in[5];
    const float* cond_b   = (const float*)d_in[6];
    const float* res_w    = (const float*)d_in[7];
    const float* res_b    = (const float*)d_in[8];
    const float* skip_w   = (const float*)d_in[9];
    const float* skip_b   = (const float*)d_in[10];
    const float* skipc_w  = (const float*)d_in[11];
    const float* skipc_b  = (const float*)d_in[12];
    const float* fc_w     = (const float*)d_in[13];
    const float* fc_b     = (const float*)d_in[14];
    const float* condf_w  = (const float*)d_in[15];
    const float* condf_b  = (const float*)d_in[16];
    const float* logits_w = (const float*)d_in[17];
    const float* logits_b = (const float*)d_in[18];

    float* wsf = (float*)d_ws;
    float* out = (float*)d_out;

    wn_gen<<<NBLK, NTHR, POOL_FL*4, stream>>>(
        enc, first_w, first_b, causal_w, causal_b, cond_w, cond_b,
        res_w, res_b, skip_w, skip_b, skipc_w, skipc_b, fc_w, fc_b,
        condf_w, condf_b, logits_w, logits_b, wsf, out);
}